// Round 10
// baseline (300.655 us; speedup 1.0000x reference)
//
#include <hip/hip_runtime.h>

#define N_NODES 4096
#define D_MODEL 128
#define QK_DIM  32
#define NHEAD   8
#define QKH     (QK_DIM * NHEAD)   // 256
#define VH      (D_MODEL * NHEAD)  // 1024

typedef _Float16 f16;
typedef _Float16 f16x8 __attribute__((ext_vector_type(8)));
typedef float    f32x4 __attribute__((ext_vector_type(4)));
typedef unsigned long long u64;

static __device__ __forceinline__ unsigned int pack_f16x2(float a, float b) {
    union { f16 h; unsigned short s; } ua, ub;
    ua.h = (f16)a; ub.h = (f16)b;
    return ((unsigned int)ub.s << 16) | (unsigned int)ua.s;
}

// ---- fused prep -----------------------------------------------------------
// mask->bits | x->xf FRAG | Wq,Wk->Wqkt FRAG | Wv->Wvt FRAG | Wo->Wot FRAG
// FRAGMENT-LINEAR layout (for gemm_body's MFMA fragment loads):
//   chunk c = (rblk*ksteps + ks)*64 + lane   (16B per chunk, lane=quad*16+col)
//   holds  M[row = rblk*16+col][k = ks*32+quad*8 .. +7]
// so a fragment load is base + lane*16B = one contiguous 1KB transaction.
// (R9 lesson: 16-line gathers were ~40% of attn; same fix applied to all
// GEMM operands here.)
__global__ __launch_bounds__(256) void prep_kernel(
    const int* __restrict__ mask, u64* __restrict__ mbits,
    const float* __restrict__ x, f16* __restrict__ xf,
    const float* __restrict__ Wq, const float* __restrict__ Wk,
    f16* __restrict__ Wqkt,
    const float* __restrict__ Wv, f16* __restrict__ Wvt,
    const float* __restrict__ Wo, f16* __restrict__ Wot) {
    const int b = blockIdx.x, t = threadIdx.x;
    if (b < 1024) {
        const int gw = b * 4 + (t >> 6), lane = t & 63;
        for (int word = gw; word < 262144; word += 4096) {
            const int v = mask[(size_t)word * 64 + lane];
            const u64 bits = __ballot(v != 0);
            if (lane == 0) mbits[word] = bits;
        }
    } else if (b < 1280) {
        // x[4096][128] -> xf frag (ksteps=4): 65536 chunks
        const int c = (b - 1024) * 256 + t;
        const int fidx = c >> 6, lanep = c & 63;
        const int rblk = fidx >> 2, ks = fidx & 3;
        const int row = rblk * 16 + (lanep & 15);
        const int kb = ks * 32 + (lanep >> 4) * 8;
        const float4 f0 = *reinterpret_cast<const float4*>(&x[(size_t)row * 128 + kb]);
        const float4 f1 = *reinterpret_cast<const float4*>(&x[(size_t)row * 128 + kb + 4]);
        f16x8 o;
        o[0] = (f16)f0.x; o[1] = (f16)f0.y; o[2] = (f16)f0.z; o[3] = (f16)f0.w;
        o[4] = (f16)f1.x; o[5] = (f16)f1.y; o[6] = (f16)f1.z; o[7] = (f16)f1.w;
        *reinterpret_cast<f16x8*>(&xf[(size_t)c * 8]) = o;
    } else if (b < 1312) {
        // Wqkt frag: N=512 (Q|K), K=128 (ksteps=4): 8192 chunks
        const int c = (b - 1280) * 256 + t;
        const int fidx = c >> 6, lanep = c & 63;
        const int nblk = fidx >> 2, ks = fidx & 3;
        const int n = nblk * 16 + (lanep & 15);
        const int kb = ks * 32 + (lanep >> 4) * 8;
        f16x8 o;
#pragma unroll
        for (int e = 0; e < 8; ++e) {
            const int k = kb + e;
            const float v = (n < 256) ? Wq[(size_t)k * 256 + n]
                                      : Wk[(size_t)k * 256 + (n - 256)];
            o[e] = (f16)v;
        }
        *reinterpret_cast<f16x8*>(&Wqkt[(size_t)c * 8]) = o;
    } else if (b < 1376) {
        // Wvt frag: N=1024, K=128 (ksteps=4): 16384 chunks
        const int c = (b - 1312) * 256 + t;
        const int fidx = c >> 6, lanep = c & 63;
        const int nblk = fidx >> 2, ks = fidx & 3;
        const int n = nblk * 16 + (lanep & 15);
        const int kb = ks * 32 + (lanep >> 4) * 8;
        f16x8 o;
#pragma unroll
        for (int e = 0; e < 8; ++e)
            o[e] = (f16)Wv[(size_t)(kb + e) * 1024 + n];
        *reinterpret_cast<f16x8*>(&Wvt[(size_t)c * 8]) = o;
    } else if (b < 1440) {
        // Wot frag: N=128, K=1024 (ksteps=32): 16384 chunks
        const int c = (b - 1376) * 256 + t;
        const int fidx = c >> 6, lanep = c & 63;
        const int nblk = fidx >> 5, ks = fidx & 31;
        const int n = nblk * 16 + (lanep & 15);
        const int kb = ks * 32 + (lanep >> 4) * 8;
        f16x8 o;
#pragma unroll
        for (int e = 0; e < 8; ++e)
            o[e] = (f16)Wo[(size_t)(kb + e) * 128 + n];
        *reinterpret_cast<f16x8*>(&Wot[(size_t)c * 8]) = o;
    }
}

// ---- GEMM body: C[M,N] = A @ W^T (+bias); A,Wt in FRAGMENT-LINEAR --------
// MODE 1: V-proj -> Vf FRAGMENT-LINEAR (LDS bounce, coalesced stores)
// MODE 3: f32 partials (no bias), k-split by bz, out offset bz*M*N
// MODE 4: QK-proj -> Qf[m][256] (n<256) + Kf FRAGMENT-LINEAR (n>=256)
// attn fragment layouts (unchanged from R9):
//   Kf 16B unit fidx = ((h*64+jblk)*4+km)*64 + lane
//   Vf 16B unit gidx = (((h*64+jblk)*4+wd)*4+t2*2+ks)*64 + lane
template <int OUT_MODE, bool DUAL_BIAS>
static __device__ __forceinline__ void gemm_body(
    const f16* __restrict__ A, const f16* __restrict__ Wt,
    const float* __restrict__ b1, const float* __restrict__ b2,
    void* __restrict__ outp, int M, int N, int K,
    int bx, int by, int bz, int nz, void* __restrict__ outp2 = nullptr) {
    const int t = threadIdx.x;
    const int w = t >> 6, lane = t & 63, quad = lane >> 4, col = lane & 15;
    const int mb = by * 64 + (w & 1) * 32;
    const int nb = bx * 64 + (w >> 1) * 32;

    const f32x4 zero = {0.f, 0.f, 0.f, 0.f};
    f32x4 acc[2][2];
    acc[0][0] = zero; acc[0][1] = zero; acc[1][0] = zero; acc[1][1] = zero;

    const int ksteps = K >> 5;
    const int kper = ksteps / nz;
    const int ks0 = bz * kper, ks1 = ks0 + kper;
    const int rblk0 = mb >> 4, nblk0 = nb >> 4;
    for (int ks = ks0; ks < ks1; ++ks) {
        const f16x8 a0 = *reinterpret_cast<const f16x8*>(
            &A[((size_t)(rblk0 * ksteps + ks) * 64 + lane) * 8]);
        const f16x8 a1 = *reinterpret_cast<const f16x8*>(
            &A[((size_t)((rblk0 + 1) * ksteps + ks) * 64 + lane) * 8]);
        const f16x8 b0 = *reinterpret_cast<const f16x8*>(
            &Wt[((size_t)(nblk0 * ksteps + ks) * 64 + lane) * 8]);
        const f16x8 bb = *reinterpret_cast<const f16x8*>(
            &Wt[((size_t)((nblk0 + 1) * ksteps + ks) * 64 + lane) * 8]);
        acc[0][0] = __builtin_amdgcn_mfma_f32_16x16x32_f16(a0, b0, acc[0][0], 0, 0, 0);
        acc[1][0] = __builtin_amdgcn_mfma_f32_16x16x32_f16(a1, b0, acc[1][0], 0, 0, 0);
        acc[0][1] = __builtin_amdgcn_mfma_f32_16x16x32_f16(a0, bb, acc[0][1], 0, 0, 0);
        acc[1][1] = __builtin_amdgcn_mfma_f32_16x16x32_f16(a1, bb, acc[1][1], 0, 0, 0);
    }

    if constexpr (OUT_MODE == 1) {
        __shared__ f16 ct[64][68];
#pragma unroll
        for (int sub = 0; sub < 2; ++sub)
#pragma unroll
            for (int snb = 0; snb < 2; ++snb) {
                const int nl = (w >> 1) * 32 + snb * 16 + col;
                const float bv = b1[nb + snb * 16 + col];
                const int ml0 = (w & 1) * 32 + sub * 16 + quad * 4;
                uint2 u;
                u.x = pack_f16x2(acc[sub][snb][0] + bv, acc[sub][snb][1] + bv);
                u.y = pack_f16x2(acc[sub][snb][2] + bv, acc[sub][snb][3] + bv);
                *reinterpret_cast<uint2*>(&ct[nl][ml0]) = u;
            }
        __syncthreads();
        const int nl = t >> 2, qtr = t & 3;
        const int n = bx * 64 + nl;          // hd index 0..1023
        const int m0 = by * 64 + qtr * 16;   // key base
        const f16x8 v0 = *reinterpret_cast<const f16x8*>(&ct[nl][qtr * 16]);
        const f16x8 v1 = *reinterpret_cast<const f16x8*>(&ct[nl][qtr * 16 + 8]);
        const int hh = n >> 7, dd = n & 127;
        const int wdv = dd >> 5, t2v = (dd >> 4) & 1, colv = dd & 15;
        {   // v0: keys m0..m0+7
            const int m = m0;
            const int jb = m >> 6, ksv = (m >> 5) & 1, qv = (m >> 3) & 3;
            const size_t gidx = ((size_t)((((hh * 64 + jb) * 4 + wdv) * 4) + t2v * 2 + ksv)) * 64 + qv * 16 + colv;
            *reinterpret_cast<f16x8*>(&((f16*)outp)[gidx * 8]) = v0;
        }
        {   // v1: keys m0+8..m0+15
            const int m = m0 + 8;
            const int jb = m >> 6, ksv = (m >> 5) & 1, qv = (m >> 3) & 3;
            const size_t gidx = ((size_t)((((hh * 64 + jb) * 4 + wdv) * 4) + t2v * 2 + ksv)) * 64 + qv * 16 + colv;
            *reinterpret_cast<f16x8*>(&((f16*)outp)[gidx * 8]) = v1;
        }
    } else if constexpr (OUT_MODE == 4) {
        f16* Qf = (f16*)outp;
        f16* Kf = (f16*)outp2;
#pragma unroll
        for (int sub = 0; sub < 2; ++sub)
#pragma unroll
            for (int snb = 0; snb < 2; ++snb) {
                const int n = nb + snb * 16 + col;
                const float bv = (DUAL_BIAS && n >= 256) ? b2[n - 256] : b1[n];
#pragma unroll
                for (int reg = 0; reg < 4; ++reg) {
                    const int m = mb + sub * 16 + quad * 4 + reg;
                    const float v  = acc[sub][snb][reg] + bv;
                    const float v2 = __shfl_xor(v, 1);
                    if ((lane & 1) == 0) {
                        const int n0 = n & ~1;
                        f16* dst;
                        if (n0 < 256) {
                            dst = &Qf[(size_t)m * 256 + n0];
                        } else {
                            const int d32 = n0 - 256;
                            const int hh = d32 >> 5, dd = d32 & 31;
                            const int lane_k = (dd >> 3) * 16 + ((m >> 2) & 15);
                            const size_t fidx = ((size_t)((hh * 64 + (m >> 6)) * 4 + (m & 3))) * 64 + lane_k;
                            dst = &Kf[fidx * 8 + (dd & 7)];
                        }
                        *reinterpret_cast<unsigned int*>(dst) = pack_f16x2(v, v2);
                    }
                }
            }
    } else {
#pragma unroll
        for (int sub = 0; sub < 2; ++sub)
#pragma unroll
            for (int snb = 0; snb < 2; ++snb) {
                const int n = nb + snb * 16 + col;
                float* ob = (float*)outp + (size_t)bz * M * N;
#pragma unroll
                for (int reg = 0; reg < 4; ++reg) {
                    const int m = mb + sub * 16 + quad * 4 + reg;
                    ob[(size_t)m * N + n] = acc[sub][snb][reg];
                }
            }
    }
}

// ---- fused QK + V projections (one launch, 24x64 grid) -------------------
__global__ __launch_bounds__(256) void proj_kernel(
    const f16* __restrict__ xf, const f16* __restrict__ Wqkt,
    const f16* __restrict__ Wvt,
    const float* __restrict__ bq, const float* __restrict__ bk,
    const float* __restrict__ bv,
    f16* __restrict__ Qf, f16* __restrict__ Kf, f16* __restrict__ Vf) {
    if (blockIdx.x < 8)
        gemm_body<4, true>(xf, Wqkt, bq, bk, Qf, N_NODES, 512, D_MODEL,
                           blockIdx.x, blockIdx.y, 0, 1, Kf);
    else
        gemm_body<1, false>(xf, Wvt, bv, bv, Vf, N_NODES, VH, D_MODEL,
                            blockIdx.x - 8, blockIdx.y, 0, 1);
}

// ---- out-projection with k-split -----------------------------------------
__global__ __launch_bounds__(256) void outproj_kernel(
    const f16* __restrict__ Rf, const f16* __restrict__ Wot,
    float* __restrict__ outp) {
    gemm_body<3, false>(Rf, Wot, nullptr, nullptr, outp, N_NODES, D_MODEL, VH,
                        blockIdx.x, blockIdx.y, blockIdx.z, gridDim.z);
}

// ---- MFMA flash attention: BYTE-IDENTICAL to R9 (105.5us, verified) ------
// HISTORY: R1 252us spill / R2,R3 WRONG @(256,2) / R5 172.8us / R6 573MB
// spill / R7 NaN (pipeline edits fragile -> structure FROZEN) / R8 traffic
// theory refuted / R9 fragment-linear K,V loads: 105.5us. This round: attn
// UNCHANGED for clean attribution; only prep/proj/outproj/merge layouts.
#define FENCED_BARRIER() do { \
    asm volatile("s_waitcnt lgkmcnt(0)\n\ts_barrier" ::: "memory"); \
    __builtin_amdgcn_sched_barrier(0); \
} while (0)

#define LOADK(KB, J) do { _Pragma("unroll") \
    for (int km = 0; km < 4; ++km) \
        KB[km] = *reinterpret_cast<const f16x8*>( \
            &Kf[((size_t)((h * 64 + ((J) >> 6)) * 4 + km) * 64 + lane) * 8]); } while (0)

#define LOADV(VB, J) do { _Pragma("unroll") \
    for (int t2 = 0; t2 < 2; ++t2) { _Pragma("unroll") \
        for (int ks = 0; ks < 2; ++ks) \
            VB[t2][ks] = *reinterpret_cast<const f16x8*>( \
                &Vf[((size_t)(((h * 64 + ((J) >> 6)) * 4 + w) * 4 + t2 * 2 + ks) * 64 + lane) * 8]); } } while (0)

#define LOADM(J) do { _Pragma("unroll") \
    for (int reg = 0; reg < 4; ++reg) \
        mr[reg] = mbits[(size_t)(q0 + 16 * w + quad * 4 + reg) * 64 + ((J) >> 6)]; } while (0)

#define LOADB(J) do { _Pragma("unroll") \
    for (int reg = 0; reg < 4; ++reg) { \
        const float4 b4 = *reinterpret_cast<const float4*>( \
            &bias[(size_t)(q0 + 16 * w + quad * 4 + reg) * N_NODES + (J) + 4 * col]); \
        bfr[reg][0] = b4.x; bfr[reg][1] = b4.y; \
        bfr[reg][2] = b4.z; bfr[reg][3] = b4.w; } } while (0)

#define TILE(KB, PSEL, PJ, POK, VJ, MJ, MOK) do { \
    f32x4 S[4]; \
    _Pragma("unroll") \
    for (int km = 0; km < 4; ++km) \
        S[km] = __builtin_amdgcn_mfma_f32_16x16x32_f16(qa, KB[km], zero, 0, 0, 0); \
    if (POK) LOADK(KB, PJ); \
    LOADV(vbT, VJ); \
    _Pragma("unroll") \
    for (int reg = 0; reg < 4; ++reg) { \
        float pk[4]; \
        _Pragma("unroll") \
        for (int km = 0; km < 4; ++km) { \
            float base = C8; \
            if (h == 0) base = __builtin_fmaf(bfr[reg][km], L2E, C8); \
            const float tt = __builtin_fmaf(S[km][reg], SCL, base); \
            const bool msk = (mr[reg] >> (4 * col + km)) & 1ull; \
            pk[km] = msk ? 0.f : __builtin_amdgcn_exp2f(tt); \
        } \
        uint2 u; \
        u.x = pack_f16x2(pk[0], pk[1]); \
        u.y = pack_f16x2(pk[2], pk[3]); \
        *reinterpret_cast<uint2*>(&ps[PSEL][16 * w + quad * 4 + reg][4 * col]) = u; \
    } \
    if (MOK) { LOADM(MJ); if (h == 0) LOADB(MJ); } \
    FENCED_BARRIER(); \
    __builtin_amdgcn_s_setprio(1); \
    _Pragma("unroll") \
    for (int ks = 0; ks < 2; ++ks) { _Pragma("unroll") \
        for (int qs = 0; qs < 4; ++qs) { \
            const f16x8 pa = *reinterpret_cast<const f16x8*>( \
                &ps[PSEL][16 * qs + col][ks * 32 + quad * 8]); \
            if (qs == w) \
                Lacc = __builtin_amdgcn_mfma_f32_16x16x32_f16(pa, onesv, Lacc, 0, 0, 0); \
            O[qs][0] = __builtin_amdgcn_mfma_f32_16x16x32_f16(pa, vbT[0][ks], O[qs][0], 0, 0, 0); \
            O[qs][1] = __builtin_amdgcn_mfma_f32_16x16x32_f16(pa, vbT[1][ks], O[qs][1], 0, 0, 0); \
        } } \
    __builtin_amdgcn_s_setprio(0); \
} while (0)

__global__ __launch_bounds__(256, 3) void attn_kernel(
    const f16* __restrict__ Qf, const f16* __restrict__ Kf,
    const f16* __restrict__ Vf,
    const u64* __restrict__ mbits, const float* __restrict__ bias,
    f16* __restrict__ R, f16* __restrict__ part, float* __restrict__ lsum) {
    const int h  = blockIdx.y;
    const int q0 = blockIdx.x * 64;
    const int t  = threadIdx.x;
    const int w = t >> 6, lane = t & 63, quad = lane >> 4, col = lane & 15;

    __shared__ f16 ps[2][64][72];   // double-buffered P tile
    __shared__ float ls[64];        // row sums for final normalization

    const f16x8 qa = *reinterpret_cast<const f16x8*>(
        &Qf[(size_t)(q0 + 16 * w + col) * 256 + h * 32 + quad * 8]);

    const f32x4 zero = {0.f, 0.f, 0.f, 0.f};
    f32x4 O[4][2];               // [qs][t2]: q 16qs+quad*4+reg, d 32w+16t2+col
#pragma unroll
    for (int qs = 0; qs < 4; ++qs) { O[qs][0] = zero; O[qs][1] = zero; }
    f32x4 Lacc = zero;
    const f16 one1 = (f16)1.f;
    const f16x8 onesv = {one1, one1, one1, one1, one1, one1, one1, one1};

    const float L2E = 1.4426950408889634f;
    const float SCL = 0.17677669529663687f * 1.4426950408889634f;  // scale*log2e
    const float C8  = -8.f * 1.4426950408889634f;                  // -MFIX*log2e
    const int jspan = N_NODES / gridDim.z;
    const int jbegin = blockIdx.z * jspan, jend = jbegin + jspan;

    f16x8 kbA[4], kbB[4];
    f16x8 vbT[2][2];
    u64   mr[4];
    float bfr[4][4];

    // prologue: two tiles of K, one tile of mask/bias (V loads in-tile)
    LOADK(kbA, jbegin);
    LOADK(kbB, jbegin + 64);
    LOADM(jbegin);
    if (h == 0) LOADB(jbegin);

    for (int j0 = jbegin; j0 < jend; j0 += 128) {
        TILE(kbA, 0, j0 + 128, j0 + 128 < jend, j0,      j0 + 64,  true);
        TILE(kbB, 1, j0 + 192, j0 + 192 < jend, j0 + 64, j0 + 128, j0 + 128 < jend);
    }

    // --- exchange row sums, normalize, store ---
    if (col == 0) {
#pragma unroll
        for (int reg = 0; reg < 4; ++reg)
            ls[16 * w + quad * 4 + reg] = Lacc[reg];
    }
    __syncthreads();

    if (gridDim.z == 1) {
        // fragment-linear Rf store (keeps outproj layout contract)
#pragma unroll
        for (int qs = 0; qs < 4; ++qs)
#pragma unroll
            for (int reg = 0; reg < 4; ++reg) {
                const float inv = 1.f / ls[16 * qs + quad * 4 + reg];
                const int q = q0 + 16 * qs + quad * 4 + reg;
#pragma unroll
                for (int t2 = 0; t2 < 2; ++t2) {
                    const int hd = h * 128 + 32 * w + 16 * t2 + col;
                    const size_t c = ((size_t)(q >> 4) * 32 + (hd >> 5)) * 64 +
                                     ((hd >> 3) & 3) * 16 + (q & 15);
                    R[c * 8 + (hd & 7)] = (f16)(O[qs][t2][reg] * inv);
                }
            }
    } else {
        const size_t seg = (size_t)(blockIdx.z * NHEAD + h) * N_NODES;
#pragma unroll
        for (int qs = 0; qs < 4; ++qs)
#pragma unroll
            for (int reg = 0; reg < 4; ++reg) {
                const float inv = 1.f / ls[16 * qs + quad * 4 + reg];
                const int q = q0 + 16 * qs + quad * 4 + reg;
#pragma unroll
                for (int t2 = 0; t2 < 2; ++t2)
                    part[(seg + q) * 128 + 32 * w + 16 * t2 + col] =
                        (f16)(O[qs][t2][reg] * inv);
            }
        if (col == 0) {
#pragma unroll
            for (int reg = 0; reg < 4; ++reg)
                lsum[seg + q0 + 16 * w + quad * 4 + reg] = Lacc[reg];
        }
    }
}

// ---- merge split partials: R = sum_z l_z*Obar_z / sum_z l_z --------------
// vectorized f16x8; writes Rf FRAGMENT-LINEAR for outproj's A-fragment loads
__global__ __launch_bounds__(256) void merge_kernel(
    const f16* __restrict__ part, const float* __restrict__ lsum,
    f16* __restrict__ R, int split) {
    const int tid = blockIdx.x * 256 + threadIdx.x;   // 8*4096*16
    const int d8 = tid & 15, q = (tid >> 4) & 4095, h = tid >> 16;
    float acc[8];
#pragma unroll
    for (int i = 0; i < 8; ++i) acc[i] = 0.f;
    float den = 0.f;
    for (int z = 0; z < split; ++z) {
        const size_t seg = (size_t)(z * NHEAD + h) * N_NODES + q;
        const float l = lsum[seg];
        const f16x8 v = *reinterpret_cast<const f16x8*>(&part[seg * 128 + 8 * d8]);
#pragma unroll
        for (int i = 0; i < 8; ++i) acc[i] += l * (float)v[i];
        den += l;
    }
    const float inv = 1.f / den;
    f16x8 o;
#pragma unroll
    for (int i = 0; i < 8; ++i) o[i] = (f16)(acc[i] * inv);
    // hd0 = h*128 + 8*d8 -> chunk c = (rblk*32 + ks)*64 + quad'*16 + col'
    const size_t c = ((size_t)(q >> 4) * 32 + h * 4 + (d8 >> 2)) * 64 +
                     (d8 & 3) * 16 + (q & 15);
    *reinterpret_cast<f16x8*>(&R[c * 8]) = o;
}

// ---- reduce out-proj k-split partials + bias (float4) --------------------
__global__ __launch_bounds__(256) void reduce_out_kernel(
    const float* __restrict__ part, const float* __restrict__ bo,
    float* __restrict__ out) {
    const int i = (blockIdx.x * 256 + threadIdx.x) * 4;   // 4096*128 floats
    float4 s = *reinterpret_cast<const float4*>(&bo[i & 127]);
#pragma unroll
    for (int z = 0; z < 4; ++z) {
        const float4 p = *reinterpret_cast<const float4*>(
            &part[(size_t)z * N_NODES * D_MODEL + i]);
        s.x += p.x; s.y += p.y; s.z += p.z; s.w += p.w;
    }
    *reinterpret_cast<float4*>(&out[i]) = s;
}

extern "C" void kernel_launch(void* const* d_in, const int* in_sizes, int n_in,
                              void* d_out, int out_size, void* d_ws, size_t ws_size,
                              hipStream_t stream) {
    const float* x  = (const float*)d_in[0];
    const int*   mk = (const int*)d_in[1];
    const float* eb = (const float*)d_in[2];
    const float* Wq = (const float*)d_in[3];
    const float* bq = (const float*)d_in[4];
    const float* Wk = (const float*)d_in[5];
    const float* bk = (const float*)d_in[6];
    const float* Wv = (const float*)d_in[7];
    const float* bv = (const float*)d_in[8];
    const float* Wo = (const float*)d_in[9];
    const float* bo = (const float*)d_in[10];
    float* out = (float*)d_out;

    char* ws = (char*)d_ws;
    u64* mbits = (u64*)(ws);                                    // 2 MB
    f16* xf16 = (f16*)(ws + 2097152);                           // 1 MB frag
    f16* Wqkt = (f16*)(ws + 3145728);                           // 128 KB frag
    f16* Wvt  = (f16*)(ws + 3276800);                           // 256 KB frag
    f16* Wot  = (f16*)(ws + 3538944);                           // 256 KB frag
    f16* Qf   = (f16*)(ws + 3801088);                           // 2 MB (node x 256)
    f16* Kf   = (f16*)(ws + 5898240);                           // 2 MB fragment-linear
    f16* Vf   = (f16*)(ws + 7995392);                           // 8 MB fragment-linear
    f16* Rf   = (f16*)(ws + 16384000);                          // 8 MB frag -> 24772608
    float* out_part = (float*)(ws + 24772608);                  // 8 MB -> 33161216
    float* lsum = (float*)(ws + 33161216);                      // 512 KB -> 33685504
    f16* part = (f16*)(ws + 33685504);                          // split*8MB -> 67239936

    // config from ws_size only (constant across calls -> graph-safe)
    int split = 1;
    if (ws_size >= 67239936ull) split = 4;
    else if (ws_size >= 50462720ull) split = 2;
    const bool ksplit_out = ws_size >= 33161216ull;

    prep_kernel<<<1440, 256, 0, stream>>>(mk, mbits, x, xf16, Wq, Wk, Wqkt, Wv, Wvt, Wo, Wot);

    proj_kernel<<<dim3(24, 64), 256, 0, stream>>>(xf16, Wqkt, Wvt, bq, bk, bv, Qf, Kf, Vf);

    attn_kernel<<<dim3(64, 8, split), 256, 0, stream>>>(Qf, Kf, Vf, mbits, eb, Rf, part, lsum);
    if (split > 1)
        merge_kernel<<<2048, 256, 0, stream>>>(part, lsum, Rf, split);

    if (ksplit_out) {
        outproj_kernel<<<dim3(2, 64, 4), 256, 0, stream>>>(Rf, Wot, out_part);
        reduce_out_kernel<<<512, 256, 0, stream>>>(out_part, bo, out);
    } else {
        // fallback: single-pass out-projection via k-split of 1
        outproj_kernel<<<dim3(2, 64, 1), 256, 0, stream>>>(Rf, Wot, out_part);
        reduce_out_kernel<<<512, 256, 0, stream>>>(out_part, bo, out);
    }
}

// Round 11
// 289.358 us; speedup vs baseline: 1.0390x; 1.0390x over previous
//
#include <hip/hip_runtime.h>

#define N_NODES 4096
#define D_MODEL 128
#define QK_DIM  32
#define NHEAD   8
#define QKH     (QK_DIM * NHEAD)   // 256
#define VH      (D_MODEL * NHEAD)  // 1024

typedef _Float16 f16;
typedef _Float16 f16x8 __attribute__((ext_vector_type(8)));
typedef float    f32x4 __attribute__((ext_vector_type(4)));
typedef unsigned long long u64;

static __device__ __forceinline__ unsigned int pack_f16x2(float a, float b) {
    union { f16 h; unsigned short s; } ua, ub;
    ua.h = (f16)a; ub.h = (f16)b;
    return ((unsigned int)ub.s << 16) | (unsigned int)ua.s;
}

// ---- fused prep -----------------------------------------------------------
// mask->bits | x->xf FRAG | Wq,Wk->Wqkt FRAG | Wv->Wvt FRAG | Wo->Wot FRAG
// FRAGMENT-LINEAR layout (for gemm_body's MFMA fragment loads):
//   chunk c = (rblk*ksteps + ks)*64 + lane   (16B per chunk, lane=quad*16+col)
//   holds  M[row = rblk*16+col][k = ks*32+quad*8 .. +7]
__global__ __launch_bounds__(256) void prep_kernel(
    const int* __restrict__ mask, u64* __restrict__ mbits,
    const float* __restrict__ x, f16* __restrict__ xf,
    const float* __restrict__ Wq, const float* __restrict__ Wk,
    f16* __restrict__ Wqkt,
    const float* __restrict__ Wv, f16* __restrict__ Wvt,
    const float* __restrict__ Wo, f16* __restrict__ Wot) {
    const int b = blockIdx.x, t = threadIdx.x;
    if (b < 1024) {
        const int gw = b * 4 + (t >> 6), lane = t & 63;
        for (int word = gw; word < 262144; word += 4096) {
            const int v = mask[(size_t)word * 64 + lane];
            const u64 bits = __ballot(v != 0);
            if (lane == 0) mbits[word] = bits;
        }
    } else if (b < 1280) {
        // x[4096][128] -> xf frag (ksteps=4): 65536 chunks
        const int c = (b - 1024) * 256 + t;
        const int fidx = c >> 6, lanep = c & 63;
        const int rblk = fidx >> 2, ks = fidx & 3;
        const int row = rblk * 16 + (lanep & 15);
        const int kb = ks * 32 + (lanep >> 4) * 8;
        const float4 f0 = *reinterpret_cast<const float4*>(&x[(size_t)row * 128 + kb]);
        const float4 f1 = *reinterpret_cast<const float4*>(&x[(size_t)row * 128 + kb + 4]);
        f16x8 o;
        o[0] = (f16)f0.x; o[1] = (f16)f0.y; o[2] = (f16)f0.z; o[3] = (f16)f0.w;
        o[4] = (f16)f1.x; o[5] = (f16)f1.y; o[6] = (f16)f1.z; o[7] = (f16)f1.w;
        *reinterpret_cast<f16x8*>(&xf[(size_t)c * 8]) = o;
    } else if (b < 1312) {
        // Wqkt frag: N=512 (Q|K), K=128 (ksteps=4): 8192 chunks
        const int c = (b - 1280) * 256 + t;
        const int fidx = c >> 6, lanep = c & 63;
        const int nblk = fidx >> 2, ks = fidx & 3;
        const int n = nblk * 16 + (lanep & 15);
        const int kb = ks * 32 + (lanep >> 4) * 8;
        f16x8 o;
#pragma unroll
        for (int e = 0; e < 8; ++e) {
            const int k = kb + e;
            const float v = (n < 256) ? Wq[(size_t)k * 256 + n]
                                      : Wk[(size_t)k * 256 + (n - 256)];
            o[e] = (f16)v;
        }
        *reinterpret_cast<f16x8*>(&Wqkt[(size_t)c * 8]) = o;
    } else if (b < 1376) {
        // Wvt frag: N=1024, K=128 (ksteps=4): 16384 chunks
        const int c = (b - 1312) * 256 + t;
        const int fidx = c >> 6, lanep = c & 63;
        const int nblk = fidx >> 2, ks = fidx & 3;
        const int n = nblk * 16 + (lanep & 15);
        const int kb = ks * 32 + (lanep >> 4) * 8;
        f16x8 o;
#pragma unroll
        for (int e = 0; e < 8; ++e)
            o[e] = (f16)Wv[(size_t)(kb + e) * 1024 + n];
        *reinterpret_cast<f16x8*>(&Wvt[(size_t)c * 8]) = o;
    } else if (b < 1440) {
        // Wot frag: N=128, K=1024 (ksteps=32): 16384 chunks
        const int c = (b - 1376) * 256 + t;
        const int fidx = c >> 6, lanep = c & 63;
        const int nblk = fidx >> 5, ks = fidx & 31;
        const int n = nblk * 16 + (lanep & 15);
        const int kb = ks * 32 + (lanep >> 4) * 8;
        f16x8 o;
#pragma unroll
        for (int e = 0; e < 8; ++e)
            o[e] = (f16)Wo[(size_t)(kb + e) * 128 + n];
        *reinterpret_cast<f16x8*>(&Wot[(size_t)c * 8]) = o;
    }
}

// ---- GEMM body: C[M,N] = A @ W^T (+bias); A,Wt in FRAGMENT-LINEAR --------
// MODE 1: V-proj -> Vf FRAGMENT-LINEAR (LDS bounce, coalesced stores)
// MODE 3: f32 partials (no bias), k-split by bz, out offset bz*M*N
// MODE 4: QK-proj -> Qf[m][256] (n<256) + Kf FRAGMENT-LINEAR (n>=256)
// attn fragment layouts (unchanged from R9):
//   Kf 16B unit fidx = ((h*64+jblk)*4+km)*64 + lane
//   Vf 16B unit gidx = (((h*64+jblk)*4+wd)*4+t2*2+ks)*64 + lane
template <int OUT_MODE, bool DUAL_BIAS>
static __device__ __forceinline__ void gemm_body(
    const f16* __restrict__ A, const f16* __restrict__ Wt,
    const float* __restrict__ b1, const float* __restrict__ b2,
    void* __restrict__ outp, int M, int N, int K,
    int bx, int by, int bz, int nz, void* __restrict__ outp2 = nullptr) {
    const int t = threadIdx.x;
    const int w = t >> 6, lane = t & 63, quad = lane >> 4, col = lane & 15;
    const int mb = by * 64 + (w & 1) * 32;
    const int nb = bx * 64 + (w >> 1) * 32;

    const f32x4 zero = {0.f, 0.f, 0.f, 0.f};
    f32x4 acc[2][2];
    acc[0][0] = zero; acc[0][1] = zero; acc[1][0] = zero; acc[1][1] = zero;

    const int ksteps = K >> 5;
    const int kper = ksteps / nz;
    const int ks0 = bz * kper, ks1 = ks0 + kper;
    const int rblk0 = mb >> 4, nblk0 = nb >> 4;
    for (int ks = ks0; ks < ks1; ++ks) {
        const f16x8 a0 = *reinterpret_cast<const f16x8*>(
            &A[((size_t)(rblk0 * ksteps + ks) * 64 + lane) * 8]);
        const f16x8 a1 = *reinterpret_cast<const f16x8*>(
            &A[((size_t)((rblk0 + 1) * ksteps + ks) * 64 + lane) * 8]);
        const f16x8 b0 = *reinterpret_cast<const f16x8*>(
            &Wt[((size_t)(nblk0 * ksteps + ks) * 64 + lane) * 8]);
        const f16x8 bb = *reinterpret_cast<const f16x8*>(
            &Wt[((size_t)((nblk0 + 1) * ksteps + ks) * 64 + lane) * 8]);
        acc[0][0] = __builtin_amdgcn_mfma_f32_16x16x32_f16(a0, b0, acc[0][0], 0, 0, 0);
        acc[1][0] = __builtin_amdgcn_mfma_f32_16x16x32_f16(a1, b0, acc[1][0], 0, 0, 0);
        acc[0][1] = __builtin_amdgcn_mfma_f32_16x16x32_f16(a0, bb, acc[0][1], 0, 0, 0);
        acc[1][1] = __builtin_amdgcn_mfma_f32_16x16x32_f16(a1, bb, acc[1][1], 0, 0, 0);
    }

    if constexpr (OUT_MODE == 1) {
        __shared__ f16 ct[64][68];
#pragma unroll
        for (int sub = 0; sub < 2; ++sub)
#pragma unroll
            for (int snb = 0; snb < 2; ++snb) {
                const int nl = (w >> 1) * 32 + snb * 16 + col;
                const float bv = b1[nb + snb * 16 + col];
                const int ml0 = (w & 1) * 32 + sub * 16 + quad * 4;
                uint2 u;
                u.x = pack_f16x2(acc[sub][snb][0] + bv, acc[sub][snb][1] + bv);
                u.y = pack_f16x2(acc[sub][snb][2] + bv, acc[sub][snb][3] + bv);
                *reinterpret_cast<uint2*>(&ct[nl][ml0]) = u;
            }
        __syncthreads();
        const int nl = t >> 2, qtr = t & 3;
        const int n = bx * 64 + nl;          // hd index 0..1023
        const int m0 = by * 64 + qtr * 16;   // key base
        const f16x8 v0 = *reinterpret_cast<const f16x8*>(&ct[nl][qtr * 16]);
        const f16x8 v1 = *reinterpret_cast<const f16x8*>(&ct[nl][qtr * 16 + 8]);
        const int hh = n >> 7, dd = n & 127;
        const int wdv = dd >> 5, t2v = (dd >> 4) & 1, colv = dd & 15;
        {   // v0: keys m0..m0+7
            const int m = m0;
            const int jb = m >> 6, ksv = (m >> 5) & 1, qv = (m >> 3) & 3;
            const size_t gidx = ((size_t)((((hh * 64 + jb) * 4 + wdv) * 4) + t2v * 2 + ksv)) * 64 + qv * 16 + colv;
            *reinterpret_cast<f16x8*>(&((f16*)outp)[gidx * 8]) = v0;
        }
        {   // v1: keys m0+8..m0+15
            const int m = m0 + 8;
            const int jb = m >> 6, ksv = (m >> 5) & 1, qv = (m >> 3) & 3;
            const size_t gidx = ((size_t)((((hh * 64 + jb) * 4 + wdv) * 4) + t2v * 2 + ksv)) * 64 + qv * 16 + colv;
            *reinterpret_cast<f16x8*>(&((f16*)outp)[gidx * 8]) = v1;
        }
    } else if constexpr (OUT_MODE == 4) {
        f16* Qf = (f16*)outp;
        f16* Kf = (f16*)outp2;
#pragma unroll
        for (int sub = 0; sub < 2; ++sub)
#pragma unroll
            for (int snb = 0; snb < 2; ++snb) {
                const int n = nb + snb * 16 + col;
                const float bv = (DUAL_BIAS && n >= 256) ? b2[n - 256] : b1[n];
#pragma unroll
                for (int reg = 0; reg < 4; ++reg) {
                    const int m = mb + sub * 16 + quad * 4 + reg;
                    const float v  = acc[sub][snb][reg] + bv;
                    const float v2 = __shfl_xor(v, 1);
                    if ((lane & 1) == 0) {
                        const int n0 = n & ~1;
                        f16* dst;
                        if (n0 < 256) {
                            dst = &Qf[(size_t)m * 256 + n0];
                        } else {
                            const int d32 = n0 - 256;
                            const int hh = d32 >> 5, dd = d32 & 31;
                            const int lane_k = (dd >> 3) * 16 + ((m >> 2) & 15);
                            const size_t fidx = ((size_t)((hh * 64 + (m >> 6)) * 4 + (m & 3))) * 64 + lane_k;
                            dst = &Kf[fidx * 8 + (dd & 7)];
                        }
                        *reinterpret_cast<unsigned int*>(dst) = pack_f16x2(v, v2);
                    }
                }
            }
    } else {
#pragma unroll
        for (int sub = 0; sub < 2; ++sub)
#pragma unroll
            for (int snb = 0; snb < 2; ++snb) {
                const int n = nb + snb * 16 + col;
                float* ob = (float*)outp + (size_t)bz * M * N;
#pragma unroll
                for (int reg = 0; reg < 4; ++reg) {
                    const int m = mb + sub * 16 + quad * 4 + reg;
                    ob[(size_t)m * N + n] = acc[sub][snb][reg];
                }
            }
    }
}

// ---- fused QK + V projections (one launch, 24x64 grid) -------------------
__global__ __launch_bounds__(256) void proj_kernel(
    const f16* __restrict__ xf, const f16* __restrict__ Wqkt,
    const f16* __restrict__ Wvt,
    const float* __restrict__ bq, const float* __restrict__ bk,
    const float* __restrict__ bv,
    f16* __restrict__ Qf, f16* __restrict__ Kf, f16* __restrict__ Vf) {
    if (blockIdx.x < 8)
        gemm_body<4, true>(xf, Wqkt, bq, bk, Qf, N_NODES, 512, D_MODEL,
                           blockIdx.x, blockIdx.y, 0, 1, Kf);
    else
        gemm_body<1, false>(xf, Wvt, bv, bv, Vf, N_NODES, VH, D_MODEL,
                            blockIdx.x - 8, blockIdx.y, 0, 1);
}

// ---- out-projection with k-split -----------------------------------------
__global__ __launch_bounds__(256) void outproj_kernel(
    const f16* __restrict__ Rf, const f16* __restrict__ Wot,
    float* __restrict__ outp) {
    gemm_body<3, false>(Rf, Wot, nullptr, nullptr, outp, N_NODES, D_MODEL, VH,
                        blockIdx.x, blockIdx.y, blockIdx.z, gridDim.z);
}

// ---- MFMA flash attention: R9 hot path, TEMPLATED epilogue ---------------
// HISTORY: R1 252us spill / R2,R3 WRONG @(256,2) / R5 172.8us / R6 573MB
// spill / R7 NaN (pipeline edits fragile -> structure FROZEN) / R8 traffic
// theory refuted / R9 fragment-linear K,V loads: 105.5us / R10: dead
// gridDim.z==1 branch rewritten for frag-Rf PERTURBED codegen (rule #19):
// attn 105.5->119.5us, WRITE 41->54MB spill, hot loop byte-identical.
// THIS VERSION: epilogue variant is a TEMPLATE param -- the hot SPLIT=true
// instantiation contains ONLY the part/lsum epilogue (no dead code at all);
// SPLIT=false (direct frag-Rf write) only compiles for the tiny-ws fallback.
#define FENCED_BARRIER() do { \
    asm volatile("s_waitcnt lgkmcnt(0)\n\ts_barrier" ::: "memory"); \
    __builtin_amdgcn_sched_barrier(0); \
} while (0)

#define LOADK(KB, J) do { _Pragma("unroll") \
    for (int km = 0; km < 4; ++km) \
        KB[km] = *reinterpret_cast<const f16x8*>( \
            &Kf[((size_t)((h * 64 + ((J) >> 6)) * 4 + km) * 64 + lane) * 8]); } while (0)

#define LOADV(VB, J) do { _Pragma("unroll") \
    for (int t2 = 0; t2 < 2; ++t2) { _Pragma("unroll") \
        for (int ks = 0; ks < 2; ++ks) \
            VB[t2][ks] = *reinterpret_cast<const f16x8*>( \
                &Vf[((size_t)(((h * 64 + ((J) >> 6)) * 4 + w) * 4 + t2 * 2 + ks) * 64 + lane) * 8]); } } while (0)

#define LOADM(J) do { _Pragma("unroll") \
    for (int reg = 0; reg < 4; ++reg) \
        mr[reg] = mbits[(size_t)(q0 + 16 * w + quad * 4 + reg) * 64 + ((J) >> 6)]; } while (0)

#define LOADB(J) do { _Pragma("unroll") \
    for (int reg = 0; reg < 4; ++reg) { \
        const float4 b4 = *reinterpret_cast<const float4*>( \
            &bias[(size_t)(q0 + 16 * w + quad * 4 + reg) * N_NODES + (J) + 4 * col]); \
        bfr[reg][0] = b4.x; bfr[reg][1] = b4.y; \
        bfr[reg][2] = b4.z; bfr[reg][3] = b4.w; } } while (0)

#define TILE(KB, PSEL, PJ, POK, VJ, MJ, MOK) do { \
    f32x4 S[4]; \
    _Pragma("unroll") \
    for (int km = 0; km < 4; ++km) \
        S[km] = __builtin_amdgcn_mfma_f32_16x16x32_f16(qa, KB[km], zero, 0, 0, 0); \
    if (POK) LOADK(KB, PJ); \
    LOADV(vbT, VJ); \
    _Pragma("unroll") \
    for (int reg = 0; reg < 4; ++reg) { \
        float pk[4]; \
        _Pragma("unroll") \
        for (int km = 0; km < 4; ++km) { \
            float base = C8; \
            if (h == 0) base = __builtin_fmaf(bfr[reg][km], L2E, C8); \
            const float tt = __builtin_fmaf(S[km][reg], SCL, base); \
            const bool msk = (mr[reg] >> (4 * col + km)) & 1ull; \
            pk[km] = msk ? 0.f : __builtin_amdgcn_exp2f(tt); \
        } \
        uint2 u; \
        u.x = pack_f16x2(pk[0], pk[1]); \
        u.y = pack_f16x2(pk[2], pk[3]); \
        *reinterpret_cast<uint2*>(&ps[PSEL][16 * w + quad * 4 + reg][4 * col]) = u; \
    } \
    if (MOK) { LOADM(MJ); if (h == 0) LOADB(MJ); } \
    FENCED_BARRIER(); \
    __builtin_amdgcn_s_setprio(1); \
    _Pragma("unroll") \
    for (int ks = 0; ks < 2; ++ks) { _Pragma("unroll") \
        for (int qs = 0; qs < 4; ++qs) { \
            const f16x8 pa = *reinterpret_cast<const f16x8*>( \
                &ps[PSEL][16 * qs + col][ks * 32 + quad * 8]); \
            if (qs == w) \
                Lacc = __builtin_amdgcn_mfma_f32_16x16x32_f16(pa, onesv, Lacc, 0, 0, 0); \
            O[qs][0] = __builtin_amdgcn_mfma_f32_16x16x32_f16(pa, vbT[0][ks], O[qs][0], 0, 0, 0); \
            O[qs][1] = __builtin_amdgcn_mfma_f32_16x16x32_f16(pa, vbT[1][ks], O[qs][1], 0, 0, 0); \
        } } \
    __builtin_amdgcn_s_setprio(0); \
} while (0)

template <bool SPLIT>
__global__ __launch_bounds__(256, 3) void attn_kernel(
    const f16* __restrict__ Qf, const f16* __restrict__ Kf,
    const f16* __restrict__ Vf,
    const u64* __restrict__ mbits, const float* __restrict__ bias,
    f16* __restrict__ R, f16* __restrict__ part, float* __restrict__ lsum) {
    const int h  = blockIdx.y;
    const int q0 = blockIdx.x * 64;
    const int t  = threadIdx.x;
    const int w = t >> 6, lane = t & 63, quad = lane >> 4, col = lane & 15;

    __shared__ f16 ps[2][64][72];   // double-buffered P tile
    __shared__ float ls[64];        // row sums for final normalization

    const f16x8 qa = *reinterpret_cast<const f16x8*>(
        &Qf[(size_t)(q0 + 16 * w + col) * 256 + h * 32 + quad * 8]);

    const f32x4 zero = {0.f, 0.f, 0.f, 0.f};
    f32x4 O[4][2];               // [qs][t2]: q 16qs+quad*4+reg, d 32w+16t2+col
#pragma unroll
    for (int qs = 0; qs < 4; ++qs) { O[qs][0] = zero; O[qs][1] = zero; }
    f32x4 Lacc = zero;
    const f16 one1 = (f16)1.f;
    const f16x8 onesv = {one1, one1, one1, one1, one1, one1, one1, one1};

    const float L2E = 1.4426950408889634f;
    const float SCL = 0.17677669529663687f * 1.4426950408889634f;  // scale*log2e
    const float C8  = -8.f * 1.4426950408889634f;                  // -MFIX*log2e
    const int jspan = N_NODES / gridDim.z;
    const int jbegin = blockIdx.z * jspan, jend = jbegin + jspan;

    f16x8 kbA[4], kbB[4];
    f16x8 vbT[2][2];
    u64   mr[4];
    float bfr[4][4];

    // prologue: two tiles of K, one tile of mask/bias (V loads in-tile)
    LOADK(kbA, jbegin);
    LOADK(kbB, jbegin + 64);
    LOADM(jbegin);
    if (h == 0) LOADB(jbegin);

    for (int j0 = jbegin; j0 < jend; j0 += 128) {
        TILE(kbA, 0, j0 + 128, j0 + 128 < jend, j0,      j0 + 64,  true);
        TILE(kbB, 1, j0 + 192, j0 + 192 < jend, j0 + 64, j0 + 128, j0 + 128 < jend);
    }

    // --- exchange row sums, normalize, store ---
    if (col == 0) {
#pragma unroll
        for (int reg = 0; reg < 4; ++reg)
            ls[16 * w + quad * 4 + reg] = Lacc[reg];
    }
    __syncthreads();

    if constexpr (SPLIT) {
        const size_t seg = (size_t)(blockIdx.z * NHEAD + h) * N_NODES;
#pragma unroll
        for (int qs = 0; qs < 4; ++qs)
#pragma unroll
            for (int reg = 0; reg < 4; ++reg) {
                const float inv = 1.f / ls[16 * qs + quad * 4 + reg];
                const int q = q0 + 16 * qs + quad * 4 + reg;
#pragma unroll
                for (int t2 = 0; t2 < 2; ++t2)
                    part[(seg + q) * 128 + 32 * w + 16 * t2 + col] =
                        (f16)(O[qs][t2][reg] * inv);
            }
        if (col == 0) {
#pragma unroll
            for (int reg = 0; reg < 4; ++reg)
                lsum[seg + q0 + 16 * w + quad * 4 + reg] = Lacc[reg];
        }
    } else {
        // direct fragment-linear Rf store (tiny-ws fallback only)
#pragma unroll
        for (int qs = 0; qs < 4; ++qs)
#pragma unroll
            for (int reg = 0; reg < 4; ++reg) {
                const float inv = 1.f / ls[16 * qs + quad * 4 + reg];
                const int q = q0 + 16 * qs + quad * 4 + reg;
#pragma unroll
                for (int t2 = 0; t2 < 2; ++t2) {
                    const int hd = h * 128 + 32 * w + 16 * t2 + col;
                    const size_t c = ((size_t)(q >> 4) * 32 + (hd >> 5)) * 64 +
                                     ((hd >> 3) & 3) * 16 + (q & 15);
                    R[c * 8 + (hd & 7)] = (f16)(O[qs][t2][reg] * inv);
                }
            }
    }
}

// ---- merge split partials: R = sum_z l_z*Obar_z / sum_z l_z --------------
// vectorized f16x8; writes Rf FRAGMENT-LINEAR for outproj's A-fragment loads
// (correct for any split>=1: part holds O/l, num/den = l*(O/l)/l = O/l)
__global__ __launch_bounds__(256) void merge_kernel(
    const f16* __restrict__ part, const float* __restrict__ lsum,
    f16* __restrict__ R, int split) {
    const int tid = blockIdx.x * 256 + threadIdx.x;   // 8*4096*16
    const int d8 = tid & 15, q = (tid >> 4) & 4095, h = tid >> 16;
    float acc[8];
#pragma unroll
    for (int i = 0; i < 8; ++i) acc[i] = 0.f;
    float den = 0.f;
    for (int z = 0; z < split; ++z) {
        const size_t seg = (size_t)(z * NHEAD + h) * N_NODES + q;
        const float l = lsum[seg];
        const f16x8 v = *reinterpret_cast<const f16x8*>(&part[seg * 128 + 8 * d8]);
#pragma unroll
        for (int i = 0; i < 8; ++i) acc[i] += l * (float)v[i];
        den += l;
    }
    const float inv = 1.f / den;
    f16x8 o;
#pragma unroll
    for (int i = 0; i < 8; ++i) o[i] = (f16)(acc[i] * inv);
    // hd0 = h*128 + 8*d8 -> chunk c = (rblk*32 + ks)*64 + quad'*16 + col'
    const size_t c = ((size_t)(q >> 4) * 32 + h * 4 + (d8 >> 2)) * 64 +
                     (d8 & 3) * 16 + (q & 15);
    *reinterpret_cast<f16x8*>(&R[c * 8]) = o;
}

// ---- reduce out-proj k-split partials + bias (float4) --------------------
__global__ __launch_bounds__(256) void reduce_out_kernel(
    const float* __restrict__ part, const float* __restrict__ bo,
    float* __restrict__ out) {
    const int i = (blockIdx.x * 256 + threadIdx.x) * 4;   // 4096*128 floats
    float4 s = *reinterpret_cast<const float4*>(&bo[i & 127]);
#pragma unroll
    for (int z = 0; z < 4; ++z) {
        const float4 p = *reinterpret_cast<const float4*>(
            &part[(size_t)z * N_NODES * D_MODEL + i]);
        s.x += p.x; s.y += p.y; s.z += p.z; s.w += p.w;
    }
    *reinterpret_cast<float4*>(&out[i]) = s;
}

extern "C" void kernel_launch(void* const* d_in, const int* in_sizes, int n_in,
                              void* d_out, int out_size, void* d_ws, size_t ws_size,
                              hipStream_t stream) {
    const float* x  = (const float*)d_in[0];
    const int*   mk = (const int*)d_in[1];
    const float* eb = (const float*)d_in[2];
    const float* Wq = (const float*)d_in[3];
    const float* bq = (const float*)d_in[4];
    const float* Wk = (const float*)d_in[5];
    const float* bk = (const float*)d_in[6];
    const float* Wv = (const float*)d_in[7];
    const float* bv = (const float*)d_in[8];
    const float* Wo = (const float*)d_in[9];
    const float* bo = (const float*)d_in[10];
    float* out = (float*)d_out;

    char* ws = (char*)d_ws;
    u64* mbits = (u64*)(ws);                                    // 2 MB
    f16* xf16 = (f16*)(ws + 2097152);                           // 1 MB frag
    f16* Wqkt = (f16*)(ws + 3145728);                           // 128 KB frag
    f16* Wvt  = (f16*)(ws + 3276800);                           // 256 KB frag
    f16* Wot  = (f16*)(ws + 3538944);                           // 256 KB frag
    f16* Qf   = (f16*)(ws + 3801088);                           // 2 MB (node x 256)
    f16* Kf   = (f16*)(ws + 5898240);                           // 2 MB fragment-linear
    f16* Vf   = (f16*)(ws + 7995392);                           // 8 MB fragment-linear
    f16* Rf   = (f16*)(ws + 16384000);                          // 8 MB frag -> 24772608
    float* out_part = (float*)(ws + 24772608);                  // 8 MB -> 33161216
    float* lsum = (float*)(ws + 33161216);                      // 512 KB -> 33685504
    f16* part = (f16*)(ws + 33685504);                          // split*8MB -> 67239936

    // config from ws_size only (constant across calls -> graph-safe)
    int split = 1;
    if (ws_size >= 67239936ull) split = 4;
    else if (ws_size >= 50462720ull) split = 2;
    // part path needs part segment (split*8MB after 33685504) + lsum
    const bool use_part = ws_size >= 33685504ull + (size_t)split * 8388608ull;
    const bool ksplit_out = ws_size >= 33161216ull;

    prep_kernel<<<1440, 256, 0, stream>>>(mk, mbits, x, xf16, Wq, Wk, Wqkt, Wv, Wvt, Wo, Wot);

    proj_kernel<<<dim3(24, 64), 256, 0, stream>>>(xf16, Wqkt, Wvt, bq, bk, bv, Qf, Kf, Vf);

    if (use_part) {
        attn_kernel<true><<<dim3(64, 8, split), 256, 0, stream>>>(
            Qf, Kf, Vf, mbits, eb, Rf, part, lsum);
        merge_kernel<<<2048, 256, 0, stream>>>(part, lsum, Rf, split);
    } else {
        attn_kernel<false><<<dim3(64, 8, 1), 256, 0, stream>>>(
            Qf, Kf, Vf, mbits, eb, Rf, part, lsum);
    }

    if (ksplit_out) {
        outproj_kernel<<<dim3(2, 64, 4), 256, 0, stream>>>(Rf, Wot, out_part);
        reduce_out_kernel<<<512, 256, 0, stream>>>(out_part, bo, out);
    } else {
        // fallback: single-pass out-projection via k-split of 1
        outproj_kernel<<<dim3(2, 64, 1), 256, 0, stream>>>(Rf, Wot, out_part);
        reduce_out_kernel<<<512, 256, 0, stream>>>(out_part, bo, out);
    }
}

// Round 12
// 288.589 us; speedup vs baseline: 1.0418x; 1.0027x over previous
//
#include <hip/hip_runtime.h>

#define N_NODES 4096
#define D_MODEL 128
#define QK_DIM  32
#define NHEAD   8
#define QKH     (QK_DIM * NHEAD)   // 256
#define VH      (D_MODEL * NHEAD)  // 1024

typedef _Float16 f16;
typedef _Float16 f16x8 __attribute__((ext_vector_type(8)));
typedef float    f32x4 __attribute__((ext_vector_type(4)));
typedef unsigned long long u64;

static __device__ __forceinline__ unsigned int pack_f16x2(float a, float b) {
    union { f16 h; unsigned short s; } ua, ub;
    ua.h = (f16)a; ub.h = (f16)b;
    return ((unsigned int)ub.s << 16) | (unsigned int)ua.s;
}

// ---- fused prep -----------------------------------------------------------
// mask->bits | x->xf FRAG | Wq,Wk->Wqkt FRAG | Wv->Wvt FRAG | Wo->Wot FRAG
// FRAGMENT-LINEAR layout (for gemm_body's MFMA fragment loads):
//   chunk c = (rblk*ksteps + ks)*64 + lane   (16B per chunk, lane=quad*16+col)
//   holds  M[row = rblk*16+col][k = ks*32+quad*8 .. +7]
__global__ __launch_bounds__(256) void prep_kernel(
    const int* __restrict__ mask, u64* __restrict__ mbits,
    const float* __restrict__ x, f16* __restrict__ xf,
    const float* __restrict__ Wq, const float* __restrict__ Wk,
    f16* __restrict__ Wqkt,
    const float* __restrict__ Wv, f16* __restrict__ Wvt,
    const float* __restrict__ Wo, f16* __restrict__ Wot) {
    const int b = blockIdx.x, t = threadIdx.x;
    if (b < 1024) {
        const int gw = b * 4 + (t >> 6), lane = t & 63;
        for (int word = gw; word < 262144; word += 4096) {
            const int v = mask[(size_t)word * 64 + lane];
            const u64 bits = __ballot(v != 0);
            if (lane == 0) mbits[word] = bits;
        }
    } else if (b < 1280) {
        // x[4096][128] -> xf frag (ksteps=4): 65536 chunks
        const int c = (b - 1024) * 256 + t;
        const int fidx = c >> 6, lanep = c & 63;
        const int rblk = fidx >> 2, ks = fidx & 3;
        const int row = rblk * 16 + (lanep & 15);
        const int kb = ks * 32 + (lanep >> 4) * 8;
        const float4 f0 = *reinterpret_cast<const float4*>(&x[(size_t)row * 128 + kb]);
        const float4 f1 = *reinterpret_cast<const float4*>(&x[(size_t)row * 128 + kb + 4]);
        f16x8 o;
        o[0] = (f16)f0.x; o[1] = (f16)f0.y; o[2] = (f16)f0.z; o[3] = (f16)f0.w;
        o[4] = (f16)f1.x; o[5] = (f16)f1.y; o[6] = (f16)f1.z; o[7] = (f16)f1.w;
        *reinterpret_cast<f16x8*>(&xf[(size_t)c * 8]) = o;
    } else if (b < 1312) {
        // Wqkt frag: N=512 (Q|K), K=128 (ksteps=4): 8192 chunks
        const int c = (b - 1280) * 256 + t;
        const int fidx = c >> 6, lanep = c & 63;
        const int nblk = fidx >> 2, ks = fidx & 3;
        const int n = nblk * 16 + (lanep & 15);
        const int kb = ks * 32 + (lanep >> 4) * 8;
        f16x8 o;
#pragma unroll
        for (int e = 0; e < 8; ++e) {
            const int k = kb + e;
            const float v = (n < 256) ? Wq[(size_t)k * 256 + n]
                                      : Wk[(size_t)k * 256 + (n - 256)];
            o[e] = (f16)v;
        }
        *reinterpret_cast<f16x8*>(&Wqkt[(size_t)c * 8]) = o;
    } else if (b < 1376) {
        // Wvt frag: N=1024, K=128 (ksteps=4): 16384 chunks
        const int c = (b - 1312) * 256 + t;
        const int fidx = c >> 6, lanep = c & 63;
        const int nblk = fidx >> 2, ks = fidx & 3;
        const int n = nblk * 16 + (lanep & 15);
        const int kb = ks * 32 + (lanep >> 4) * 8;
        f16x8 o;
#pragma unroll
        for (int e = 0; e < 8; ++e)
            o[e] = (f16)Wv[(size_t)(kb + e) * 1024 + n];
        *reinterpret_cast<f16x8*>(&Wvt[(size_t)c * 8]) = o;
    } else if (b < 1440) {
        // Wot frag: N=128, K=1024 (ksteps=32): 16384 chunks
        const int c = (b - 1376) * 256 + t;
        const int fidx = c >> 6, lanep = c & 63;
        const int nblk = fidx >> 5, ks = fidx & 31;
        const int n = nblk * 16 + (lanep & 15);
        const int kb = ks * 32 + (lanep >> 4) * 8;
        f16x8 o;
#pragma unroll
        for (int e = 0; e < 8; ++e)
            o[e] = (f16)Wo[(size_t)(kb + e) * 128 + n];
        *reinterpret_cast<f16x8*>(&Wot[(size_t)c * 8]) = o;
    }
}

// ---- GEMM body: C[M,N] = A @ W^T (+bias); A,Wt in FRAGMENT-LINEAR --------
// R12: ALL epilogues now LDS-bounce to coalesced stores (R11 lesson: the
// remaining non-attn slack is scattered STORES -- MODE3 was 16 scalar f32
// stores/thread at stride 512B (16-line scatter per instr), MODE4 was 4B
// global scatter via shfl. Loads were fixed in R9/R10; this fixes stores.)
// MODE 1: V-proj -> Vf FRAGMENT-LINEAR (LDS bounce, window-local 16B stores)
// MODE 3: f32 partials -> out_part TILED-LINEAR: tile(bz*128+by*2+bx) is a
//         contiguous 16KB row-major 64x64 block; stores perfectly linear.
// MODE 4: QK-proj: LDS bounce -> Qf[m][256] row-major f16x8 runs (bx<4) or
//         Kf fragment 16B chunks, window-local <=8KB (bx>=4).
// attn fragment layouts (unchanged from R9):
//   Kf 16B unit fidx = ((h*64+jblk)*4+km)*64 + lane
//   Vf 16B unit gidx = (((h*64+jblk)*4+wd)*4+t2*2+ks)*64 + lane
template <int OUT_MODE, bool DUAL_BIAS>
static __device__ __forceinline__ void gemm_body(
    const f16* __restrict__ A, const f16* __restrict__ Wt,
    const float* __restrict__ b1, const float* __restrict__ b2,
    void* __restrict__ outp, int M, int N, int K,
    int bx, int by, int bz, int nz, void* __restrict__ outp2 = nullptr) {
    const int t = threadIdx.x;
    const int w = t >> 6, lane = t & 63, quad = lane >> 4, col = lane & 15;
    const int mb = by * 64 + (w & 1) * 32;
    const int nb = bx * 64 + (w >> 1) * 32;

    const f32x4 zero = {0.f, 0.f, 0.f, 0.f};
    f32x4 acc[2][2];
    acc[0][0] = zero; acc[0][1] = zero; acc[1][0] = zero; acc[1][1] = zero;

    const int ksteps = K >> 5;
    const int kper = ksteps / nz;
    const int ks0 = bz * kper, ks1 = ks0 + kper;
    const int rblk0 = mb >> 4, nblk0 = nb >> 4;
    for (int ks = ks0; ks < ks1; ++ks) {
        const f16x8 a0 = *reinterpret_cast<const f16x8*>(
            &A[((size_t)(rblk0 * ksteps + ks) * 64 + lane) * 8]);
        const f16x8 a1 = *reinterpret_cast<const f16x8*>(
            &A[((size_t)((rblk0 + 1) * ksteps + ks) * 64 + lane) * 8]);
        const f16x8 b0 = *reinterpret_cast<const f16x8*>(
            &Wt[((size_t)(nblk0 * ksteps + ks) * 64 + lane) * 8]);
        const f16x8 bb = *reinterpret_cast<const f16x8*>(
            &Wt[((size_t)((nblk0 + 1) * ksteps + ks) * 64 + lane) * 8]);
        acc[0][0] = __builtin_amdgcn_mfma_f32_16x16x32_f16(a0, b0, acc[0][0], 0, 0, 0);
        acc[1][0] = __builtin_amdgcn_mfma_f32_16x16x32_f16(a1, b0, acc[1][0], 0, 0, 0);
        acc[0][1] = __builtin_amdgcn_mfma_f32_16x16x32_f16(a0, bb, acc[0][1], 0, 0, 0);
        acc[1][1] = __builtin_amdgcn_mfma_f32_16x16x32_f16(a1, bb, acc[1][1], 0, 0, 0);
    }

    if constexpr (OUT_MODE == 1) {
        __shared__ f16 ct[64][68];
#pragma unroll
        for (int sub = 0; sub < 2; ++sub)
#pragma unroll
            for (int snb = 0; snb < 2; ++snb) {
                const int nl = (w >> 1) * 32 + snb * 16 + col;
                const float bv = b1[nb + snb * 16 + col];
                const int ml0 = (w & 1) * 32 + sub * 16 + quad * 4;
                uint2 u;
                u.x = pack_f16x2(acc[sub][snb][0] + bv, acc[sub][snb][1] + bv);
                u.y = pack_f16x2(acc[sub][snb][2] + bv, acc[sub][snb][3] + bv);
                *reinterpret_cast<uint2*>(&ct[nl][ml0]) = u;
            }
        __syncthreads();
        const int nl = t >> 2, qtr = t & 3;
        const int n = bx * 64 + nl;          // hd index 0..1023
        const int m0 = by * 64 + qtr * 16;   // key base
        const f16x8 v0 = *reinterpret_cast<const f16x8*>(&ct[nl][qtr * 16]);
        const f16x8 v1 = *reinterpret_cast<const f16x8*>(&ct[nl][qtr * 16 + 8]);
        const int hh = n >> 7, dd = n & 127;
        const int wdv = dd >> 5, t2v = (dd >> 4) & 1, colv = dd & 15;
        {   // v0: keys m0..m0+7
            const int m = m0;
            const int jb = m >> 6, ksv = (m >> 5) & 1, qv = (m >> 3) & 3;
            const size_t gidx = ((size_t)((((hh * 64 + jb) * 4 + wdv) * 4) + t2v * 2 + ksv)) * 64 + qv * 16 + colv;
            *reinterpret_cast<f16x8*>(&((f16*)outp)[gidx * 8]) = v0;
        }
        {   // v1: keys m0+8..m0+15
            const int m = m0 + 8;
            const int jb = m >> 6, ksv = (m >> 5) & 1, qv = (m >> 3) & 3;
            const size_t gidx = ((size_t)((((hh * 64 + jb) * 4 + wdv) * 4) + t2v * 2 + ksv)) * 64 + qv * 16 + colv;
            *reinterpret_cast<f16x8*>(&((f16*)outp)[gidx * 8]) = v1;
        }
    } else if constexpr (OUT_MODE == 4) {
        f16* Qf = (f16*)outp;
        f16* Kf = (f16*)outp2;
        __shared__ f16 ct[64][72];   // [m_local][n_local]
#pragma unroll
        for (int sub = 0; sub < 2; ++sub)
#pragma unroll
            for (int snb = 0; snb < 2; ++snb) {
                const int n = nb + snb * 16 + col;
                const float bv = (DUAL_BIAS && n >= 256) ? b2[n - 256] : b1[n];
                const int nl = (w >> 1) * 32 + snb * 16 + col;
                const int ml0 = (w & 1) * 32 + sub * 16 + quad * 4;
#pragma unroll
                for (int reg = 0; reg < 4; ++reg)
                    ct[ml0 + reg][nl] = (f16)(acc[sub][snb][reg] + bv);
            }
        __syncthreads();
        if (bx < 4) {
            // pure Q region: row-major Qf[m][256], coalesced f16x8 runs
#pragma unroll
            for (int p = 0; p < 2; ++p) {
                const int C = p * 256 + t;           // 512 f16x8 chunks
                const int r = C >> 3, c8 = (C & 7) * 8;
                const f16x8 v = *reinterpret_cast<const f16x8*>(&ct[r][c8]);
                *reinterpret_cast<f16x8*>(
                    &Qf[(size_t)(by * 64 + r) * 256 + bx * 64 + c8]) = v;
            }
        } else {
            // K region: fragment 16B chunks, window-local stores
#pragma unroll
            for (int p = 0; p < 2; ++p) {
                const int C = p * 256 + t;
                const int r = C >> 3, c8 = (C & 7) * 8;   // key_local, d64
                const int key = by * 64 + r;
                const int hh = (bx - 4) * 2 + (c8 >> 5);
                const int dd = c8 & 31;
                const f16x8 v = *reinterpret_cast<const f16x8*>(&ct[r][c8]);
                const int lane_k = (dd >> 3) * 16 + ((key >> 2) & 15);
                const size_t fidx =
                    ((size_t)(hh * 64 + (key >> 6)) * 4 + (key & 3)) * 64 + lane_k;
                *reinterpret_cast<f16x8*>(&Kf[fidx * 8]) = v;
            }
        }
    } else {
        // MODE 3: tiled-linear out_part
        __shared__ float cs[64][65];
#pragma unroll
        for (int sub = 0; sub < 2; ++sub)
#pragma unroll
            for (int snb = 0; snb < 2; ++snb) {
                const int nl = (w >> 1) * 32 + snb * 16 + col;
                const int ml0 = (w & 1) * 32 + sub * 16 + quad * 4;
#pragma unroll
                for (int reg = 0; reg < 4; ++reg)
                    cs[ml0 + reg][nl] = acc[sub][snb][reg];
            }
        __syncthreads();
        float* tb = (float*)outp + (size_t)(bz * 128 + by * 2 + bx) * 4096;
#pragma unroll
        for (int p = 0; p < 4; ++p) {
            const int F = p * 256 + t;            // 1024 float4 chunks
            const int r = F >> 4, c4 = (F & 15) * 4;
            float4 v;
            v.x = cs[r][c4]; v.y = cs[r][c4 + 1];
            v.z = cs[r][c4 + 2]; v.w = cs[r][c4 + 3];
            *reinterpret_cast<float4*>(&tb[(size_t)F * 4]) = v;
        }
    }
}

// ---- fused QK + V projections (one launch, 24x64 grid) -------------------
__global__ __launch_bounds__(256) void proj_kernel(
    const f16* __restrict__ xf, const f16* __restrict__ Wqkt,
    const f16* __restrict__ Wvt,
    const float* __restrict__ bq, const float* __restrict__ bk,
    const float* __restrict__ bv,
    f16* __restrict__ Qf, f16* __restrict__ Kf, f16* __restrict__ Vf) {
    if (blockIdx.x < 8)
        gemm_body<4, true>(xf, Wqkt, bq, bk, Qf, N_NODES, 512, D_MODEL,
                           blockIdx.x, blockIdx.y, 0, 1, Kf);
    else
        gemm_body<1, false>(xf, Wvt, bv, bv, Vf, N_NODES, VH, D_MODEL,
                            blockIdx.x - 8, blockIdx.y, 0, 1);
}

// ---- out-projection with k-split (tiled-linear partials) -----------------
__global__ __launch_bounds__(256) void outproj_kernel(
    const f16* __restrict__ Rf, const f16* __restrict__ Wot,
    float* __restrict__ outp) {
    gemm_body<3, false>(Rf, Wot, nullptr, nullptr, outp, N_NODES, D_MODEL, VH,
                        blockIdx.x, blockIdx.y, blockIdx.z, gridDim.z);
}

// ---- MFMA flash attention: BYTE-IDENTICAL to R11 -------------------------
// HISTORY: R1 252us spill / R2,R3 WRONG @(256,2) / R5 172.8us / R6 573MB
// spill / R7 NaN (pipeline edits fragile -> structure FROZEN) / R8 traffic
// theory refuted / R9 frag-linear K,V loads: 105.5us / R10 dead-branch
// perturbation (rule #19) / R11 templated epilogue: 114.6us, spill gone.
// R12: attn untouched; only proj/outproj/reduce store paths changed.
#define FENCED_BARRIER() do { \
    asm volatile("s_waitcnt lgkmcnt(0)\n\ts_barrier" ::: "memory"); \
    __builtin_amdgcn_sched_barrier(0); \
} while (0)

#define LOADK(KB, J) do { _Pragma("unroll") \
    for (int km = 0; km < 4; ++km) \
        KB[km] = *reinterpret_cast<const f16x8*>( \
            &Kf[((size_t)((h * 64 + ((J) >> 6)) * 4 + km) * 64 + lane) * 8]); } while (0)

#define LOADV(VB, J) do { _Pragma("unroll") \
    for (int t2 = 0; t2 < 2; ++t2) { _Pragma("unroll") \
        for (int ks = 0; ks < 2; ++ks) \
            VB[t2][ks] = *reinterpret_cast<const f16x8*>( \
                &Vf[((size_t)(((h * 64 + ((J) >> 6)) * 4 + w) * 4 + t2 * 2 + ks) * 64 + lane) * 8]); } } while (0)

#define LOADM(J) do { _Pragma("unroll") \
    for (int reg = 0; reg < 4; ++reg) \
        mr[reg] = mbits[(size_t)(q0 + 16 * w + quad * 4 + reg) * 64 + ((J) >> 6)]; } while (0)

#define LOADB(J) do { _Pragma("unroll") \
    for (int reg = 0; reg < 4; ++reg) { \
        const float4 b4 = *reinterpret_cast<const float4*>( \
            &bias[(size_t)(q0 + 16 * w + quad * 4 + reg) * N_NODES + (J) + 4 * col]); \
        bfr[reg][0] = b4.x; bfr[reg][1] = b4.y; \
        bfr[reg][2] = b4.z; bfr[reg][3] = b4.w; } } while (0)

#define TILE(KB, PSEL, PJ, POK, VJ, MJ, MOK) do { \
    f32x4 S[4]; \
    _Pragma("unroll") \
    for (int km = 0; km < 4; ++km) \
        S[km] = __builtin_amdgcn_mfma_f32_16x16x32_f16(qa, KB[km], zero, 0, 0, 0); \
    if (POK) LOADK(KB, PJ); \
    LOADV(vbT, VJ); \
    _Pragma("unroll") \
    for (int reg = 0; reg < 4; ++reg) { \
        float pk[4]; \
        _Pragma("unroll") \
        for (int km = 0; km < 4; ++km) { \
            float base = C8; \
            if (h == 0) base = __builtin_fmaf(bfr[reg][km], L2E, C8); \
            const float tt = __builtin_fmaf(S[km][reg], SCL, base); \
            const bool msk = (mr[reg] >> (4 * col + km)) & 1ull; \
            pk[km] = msk ? 0.f : __builtin_amdgcn_exp2f(tt); \
        } \
        uint2 u; \
        u.x = pack_f16x2(pk[0], pk[1]); \
        u.y = pack_f16x2(pk[2], pk[3]); \
        *reinterpret_cast<uint2*>(&ps[PSEL][16 * w + quad * 4 + reg][4 * col]) = u; \
    } \
    if (MOK) { LOADM(MJ); if (h == 0) LOADB(MJ); } \
    FENCED_BARRIER(); \
    __builtin_amdgcn_s_setprio(1); \
    _Pragma("unroll") \
    for (int ks = 0; ks < 2; ++ks) { _Pragma("unroll") \
        for (int qs = 0; qs < 4; ++qs) { \
            const f16x8 pa = *reinterpret_cast<const f16x8*>( \
                &ps[PSEL][16 * qs + col][ks * 32 + quad * 8]); \
            if (qs == w) \
                Lacc = __builtin_amdgcn_mfma_f32_16x16x32_f16(pa, onesv, Lacc, 0, 0, 0); \
            O[qs][0] = __builtin_amdgcn_mfma_f32_16x16x32_f16(pa, vbT[0][ks], O[qs][0], 0, 0, 0); \
            O[qs][1] = __builtin_amdgcn_mfma_f32_16x16x32_f16(pa, vbT[1][ks], O[qs][1], 0, 0, 0); \
        } } \
    __builtin_amdgcn_s_setprio(0); \
} while (0)

template <bool SPLIT>
__global__ __launch_bounds__(256, 3) void attn_kernel(
    const f16* __restrict__ Qf, const f16* __restrict__ Kf,
    const f16* __restrict__ Vf,
    const u64* __restrict__ mbits, const float* __restrict__ bias,
    f16* __restrict__ R, f16* __restrict__ part, float* __restrict__ lsum) {
    const int h  = blockIdx.y;
    const int q0 = blockIdx.x * 64;
    const int t  = threadIdx.x;
    const int w = t >> 6, lane = t & 63, quad = lane >> 4, col = lane & 15;

    __shared__ f16 ps[2][64][72];   // double-buffered P tile
    __shared__ float ls[64];        // row sums for final normalization

    const f16x8 qa = *reinterpret_cast<const f16x8*>(
        &Qf[(size_t)(q0 + 16 * w + col) * 256 + h * 32 + quad * 8]);

    const f32x4 zero = {0.f, 0.f, 0.f, 0.f};
    f32x4 O[4][2];               // [qs][t2]: q 16qs+quad*4+reg, d 32w+16t2+col
#pragma unroll
    for (int qs = 0; qs < 4; ++qs) { O[qs][0] = zero; O[qs][1] = zero; }
    f32x4 Lacc = zero;
    const f16 one1 = (f16)1.f;
    const f16x8 onesv = {one1, one1, one1, one1, one1, one1, one1, one1};

    const float L2E = 1.4426950408889634f;
    const float SCL = 0.17677669529663687f * 1.4426950408889634f;  // scale*log2e
    const float C8  = -8.f * 1.4426950408889634f;                  // -MFIX*log2e
    const int jspan = N_NODES / gridDim.z;
    const int jbegin = blockIdx.z * jspan, jend = jbegin + jspan;

    f16x8 kbA[4], kbB[4];
    f16x8 vbT[2][2];
    u64   mr[4];
    float bfr[4][4];

    // prologue: two tiles of K, one tile of mask/bias (V loads in-tile)
    LOADK(kbA, jbegin);
    LOADK(kbB, jbegin + 64);
    LOADM(jbegin);
    if (h == 0) LOADB(jbegin);

    for (int j0 = jbegin; j0 < jend; j0 += 128) {
        TILE(kbA, 0, j0 + 128, j0 + 128 < jend, j0,      j0 + 64,  true);
        TILE(kbB, 1, j0 + 192, j0 + 192 < jend, j0 + 64, j0 + 128, j0 + 128 < jend);
    }

    // --- exchange row sums, normalize, store ---
    if (col == 0) {
#pragma unroll
        for (int reg = 0; reg < 4; ++reg)
            ls[16 * w + quad * 4 + reg] = Lacc[reg];
    }
    __syncthreads();

    if constexpr (SPLIT) {
        const size_t seg = (size_t)(blockIdx.z * NHEAD + h) * N_NODES;
#pragma unroll
        for (int qs = 0; qs < 4; ++qs)
#pragma unroll
            for (int reg = 0; reg < 4; ++reg) {
                const float inv = 1.f / ls[16 * qs + quad * 4 + reg];
                const int q = q0 + 16 * qs + quad * 4 + reg;
#pragma unroll
                for (int t2 = 0; t2 < 2; ++t2)
                    part[(seg + q) * 128 + 32 * w + 16 * t2 + col] =
                        (f16)(O[qs][t2][reg] * inv);
            }
        if (col == 0) {
#pragma unroll
            for (int reg = 0; reg < 4; ++reg)
                lsum[seg + q0 + 16 * w + quad * 4 + reg] = Lacc[reg];
        }
    } else {
        // direct fragment-linear Rf store (tiny-ws fallback only)
#pragma unroll
        for (int qs = 0; qs < 4; ++qs)
#pragma unroll
            for (int reg = 0; reg < 4; ++reg) {
                const float inv = 1.f / ls[16 * qs + quad * 4 + reg];
                const int q = q0 + 16 * qs + quad * 4 + reg;
#pragma unroll
                for (int t2 = 0; t2 < 2; ++t2) {
                    const int hd = h * 128 + 32 * w + 16 * t2 + col;
                    const size_t c = ((size_t)(q >> 4) * 32 + (hd >> 5)) * 64 +
                                     ((hd >> 3) & 3) * 16 + (q & 15);
                    R[c * 8 + (hd & 7)] = (f16)(O[qs][t2][reg] * inv);
                }
            }
    }
}

// ---- merge split partials: R = sum_z l_z*Obar_z / sum_z l_z --------------
// vectorized f16x8; writes Rf FRAGMENT-LINEAR for outproj's A-fragment loads
__global__ __launch_bounds__(256) void merge_kernel(
    const f16* __restrict__ part, const float* __restrict__ lsum,
    f16* __restrict__ R, int split) {
    const int tid = blockIdx.x * 256 + threadIdx.x;   // 8*4096*16
    const int d8 = tid & 15, q = (tid >> 4) & 4095, h = tid >> 16;
    float acc[8];
#pragma unroll
    for (int i = 0; i < 8; ++i) acc[i] = 0.f;
    float den = 0.f;
    for (int z = 0; z < split; ++z) {
        const size_t seg = (size_t)(z * NHEAD + h) * N_NODES + q;
        const float l = lsum[seg];
        const f16x8 v = *reinterpret_cast<const f16x8*>(&part[seg * 128 + 8 * d8]);
#pragma unroll
        for (int i = 0; i < 8; ++i) acc[i] += l * (float)v[i];
        den += l;
    }
    const float inv = 1.f / den;
    f16x8 o;
#pragma unroll
    for (int i = 0; i < 8; ++i) o[i] = (f16)(acc[i] * inv);
    // hd0 = h*128 + 8*d8 -> chunk c = (rblk*32 + ks)*64 + quad'*16 + col'
    const size_t c = ((size_t)(q >> 4) * 32 + h * 4 + (d8 >> 2)) * 64 +
                     (d8 & 3) * 16 + (q & 15);
    *reinterpret_cast<f16x8*>(&R[c * 8]) = o;
}

// ---- reduce out-proj tiled partials + bias (float4, coalesced) -----------
__global__ __launch_bounds__(256) void reduce_out_kernel(
    const float* __restrict__ part, const float* __restrict__ bo,
    float* __restrict__ out) {
    const int i = (blockIdx.x * 256 + threadIdx.x) * 4;   // 4096*128 floats
    const int q = i >> 7, n = i & 127;
    const size_t telem = (size_t)(q & 63) * 64 + (n & 63);
    float4 s = *reinterpret_cast<const float4*>(&bo[n]);
#pragma unroll
    for (int z = 0; z < 4; ++z) {
        const float* tb = part +
            (size_t)(z * 128 + (q >> 6) * 2 + (n >> 6)) * 4096;
        const float4 p = *reinterpret_cast<const float4*>(&tb[telem]);
        s.x += p.x; s.y += p.y; s.z += p.z; s.w += p.w;
    }
    *reinterpret_cast<float4*>(&out[i]) = s;
}

extern "C" void kernel_launch(void* const* d_in, const int* in_sizes, int n_in,
                              void* d_out, int out_size, void* d_ws, size_t ws_size,
                              hipStream_t stream) {
    const float* x  = (const float*)d_in[0];
    const int*   mk = (const int*)d_in[1];
    const float* eb = (const float*)d_in[2];
    const float* Wq = (const float*)d_in[3];
    const float* bq = (const float*)d_in[4];
    const float* Wk = (const float*)d_in[5];
    const float* bk = (const float*)d_in[6];
    const float* Wv = (const float*)d_in[7];
    const float* bv = (const float*)d_in[8];
    const float* Wo = (const float*)d_in[9];
    const float* bo = (const float*)d_in[10];
    float* out = (float*)d_out;

    char* ws = (char*)d_ws;
    u64* mbits = (u64*)(ws);                                    // 2 MB
    f16* xf16 = (f16*)(ws + 2097152);                           // 1 MB frag
    f16* Wqkt = (f16*)(ws + 3145728);                           // 128 KB frag
    f16* Wvt  = (f16*)(ws + 3276800);                           // 256 KB frag
    f16* Wot  = (f16*)(ws + 3538944);                           // 256 KB frag
    f16* Qf   = (f16*)(ws + 3801088);                           // 2 MB (node x 256)
    f16* Kf   = (f16*)(ws + 5898240);                           // 2 MB fragment-linear
    f16* Vf   = (f16*)(ws + 7995392);                           // 8 MB fragment-linear
    f16* Rf   = (f16*)(ws + 16384000);                          // 8 MB frag -> 24772608
    float* out_part = (float*)(ws + 24772608);                  // 8 MB tiled -> 33161216
    float* lsum = (float*)(ws + 33161216);                      // 512 KB -> 33685504
    f16* part = (f16*)(ws + 33685504);                          // split*8MB -> 67239936

    // config from ws_size only (constant across calls -> graph-safe)
    int split = 1;
    if (ws_size >= 67239936ull) split = 4;
    else if (ws_size >= 50462720ull) split = 2;
    // part path needs part segment (split*8MB after 33685504) + lsum
    const bool use_part = ws_size >= 33685504ull + (size_t)split * 8388608ull;
    const bool ksplit_out = ws_size >= 33161216ull;

    prep_kernel<<<1440, 256, 0, stream>>>(mk, mbits, x, xf16, Wq, Wk, Wqkt, Wv, Wvt, Wo, Wot);

    proj_kernel<<<dim3(24, 64), 256, 0, stream>>>(xf16, Wqkt, Wvt, bq, bk, bv, Qf, Kf, Vf);

    if (use_part) {
        attn_kernel<true><<<dim3(64, 8, split), 256, 0, stream>>>(
            Qf, Kf, Vf, mbits, eb, Rf, part, lsum);
        merge_kernel<<<2048, 256, 0, stream>>>(part, lsum, Rf, split);
    } else {
        attn_kernel<false><<<dim3(64, 8, 1), 256, 0, stream>>>(
            Qf, Kf, Vf, mbits, eb, Rf, part, lsum);
    }

    if (ksplit_out) {
        outproj_kernel<<<dim3(2, 64, 4), 256, 0, stream>>>(Rf, Wot, out_part);
        reduce_out_kernel<<<512, 256, 0, stream>>>(out_part, bo, out);
    } else {
        // fallback: single-pass out-projection (never taken at bench ws)
        outproj_kernel<<<dim3(2, 64, 1), 256, 0, stream>>>(Rf, Wot, out_part);
        reduce_out_kernel<<<512, 256, 0, stream>>>(out_part, bo, out);
    }
}

// Round 14
// 281.922 us; speedup vs baseline: 1.0664x; 1.0237x over previous
//
#include <hip/hip_runtime.h>

#define N_NODES 4096
#define D_MODEL 128
#define QK_DIM  32
#define NHEAD   8
#define QKH     (QK_DIM * NHEAD)   // 256
#define VH      (D_MODEL * NHEAD)  // 1024

typedef _Float16 f16;
typedef _Float16 f16x8 __attribute__((ext_vector_type(8)));
typedef float    f32x4 __attribute__((ext_vector_type(4)));
typedef unsigned long long u64;

static __device__ __forceinline__ unsigned int pack_f16x2(float a, float b) {
    union { f16 h; unsigned short s; } ua, ub;
    ua.h = (f16)a; ub.h = (f16)b;
    return ((unsigned int)ub.s << 16) | (unsigned int)ua.s;
}

// single-instruction f32x2 -> f16x2 pack (v_cvt_pkrtz_f16_f32); RTZ rounding
// is self-consistent in attn (L is computed from the same rounded ps).
// NOTE: the builtin returns __fp16 ext_vector_type(2) -- union must use that
// exact type (R13 compile error: assignment to _Float16 vector rejected).
typedef __fp16 fp16x2_builtin __attribute__((ext_vector_type(2)));
static __device__ __forceinline__ unsigned int pkrtz(float a, float b) {
    union { fp16x2_builtin h; unsigned int u; } cv;
    cv.h = __builtin_amdgcn_cvt_pkrtz(a, b);
    return cv.u;
}

// ---- fused prep -----------------------------------------------------------
// mask->bits | x->xf FRAG | Wq,Wk->Wqkt FRAG | Wv->Wvt FRAG | Wo->Wot FRAG
// FRAGMENT-LINEAR layout (for gemm_body's MFMA fragment loads):
//   chunk c = (rblk*ksteps + ks)*64 + lane   (16B per chunk, lane=quad*16+col)
//   holds  M[row = rblk*16+col][k = ks*32+quad*8 .. +7]
__global__ __launch_bounds__(256) void prep_kernel(
    const int* __restrict__ mask, u64* __restrict__ mbits,
    const float* __restrict__ x, f16* __restrict__ xf,
    const float* __restrict__ Wq, const float* __restrict__ Wk,
    f16* __restrict__ Wqkt,
    const float* __restrict__ Wv, f16* __restrict__ Wvt,
    const float* __restrict__ Wo, f16* __restrict__ Wot) {
    const int b = blockIdx.x, t = threadIdx.x;
    if (b < 1024) {
        const int gw = b * 4 + (t >> 6), lane = t & 63;
        for (int word = gw; word < 262144; word += 4096) {
            const int v = mask[(size_t)word * 64 + lane];
            const u64 bits = __ballot(v != 0);
            if (lane == 0) mbits[word] = bits;
        }
    } else if (b < 1280) {
        // x[4096][128] -> xf frag (ksteps=4): 65536 chunks
        const int c = (b - 1024) * 256 + t;
        const int fidx = c >> 6, lanep = c & 63;
        const int rblk = fidx >> 2, ks = fidx & 3;
        const int row = rblk * 16 + (lanep & 15);
        const int kb = ks * 32 + (lanep >> 4) * 8;
        const float4 f0 = *reinterpret_cast<const float4*>(&x[(size_t)row * 128 + kb]);
        const float4 f1 = *reinterpret_cast<const float4*>(&x[(size_t)row * 128 + kb + 4]);
        f16x8 o;
        o[0] = (f16)f0.x; o[1] = (f16)f0.y; o[2] = (f16)f0.z; o[3] = (f16)f0.w;
        o[4] = (f16)f1.x; o[5] = (f16)f1.y; o[6] = (f16)f1.z; o[7] = (f16)f1.w;
        *reinterpret_cast<f16x8*>(&xf[(size_t)c * 8]) = o;
    } else if (b < 1312) {
        // Wqkt frag: N=512 (Q|K), K=128 (ksteps=4): 8192 chunks
        const int c = (b - 1280) * 256 + t;
        const int fidx = c >> 6, lanep = c & 63;
        const int nblk = fidx >> 2, ks = fidx & 3;
        const int n = nblk * 16 + (lanep & 15);
        const int kb = ks * 32 + (lanep >> 4) * 8;
        f16x8 o;
#pragma unroll
        for (int e = 0; e < 8; ++e) {
            const int k = kb + e;
            const float v = (n < 256) ? Wq[(size_t)k * 256 + n]
                                      : Wk[(size_t)k * 256 + (n - 256)];
            o[e] = (f16)v;
        }
        *reinterpret_cast<f16x8*>(&Wqkt[(size_t)c * 8]) = o;
    } else if (b < 1376) {
        // Wvt frag: N=1024, K=128 (ksteps=4): 16384 chunks
        const int c = (b - 1312) * 256 + t;
        const int fidx = c >> 6, lanep = c & 63;
        const int nblk = fidx >> 2, ks = fidx & 3;
        const int n = nblk * 16 + (lanep & 15);
        const int kb = ks * 32 + (lanep >> 4) * 8;
        f16x8 o;
#pragma unroll
        for (int e = 0; e < 8; ++e)
            o[e] = (f16)Wv[(size_t)(kb + e) * 1024 + n];
        *reinterpret_cast<f16x8*>(&Wvt[(size_t)c * 8]) = o;
    } else if (b < 1440) {
        // Wot frag: N=128, K=1024 (ksteps=32): 16384 chunks
        const int c = (b - 1376) * 256 + t;
        const int fidx = c >> 6, lanep = c & 63;
        const int nblk = fidx >> 5, ks = fidx & 31;
        const int n = nblk * 16 + (lanep & 15);
        const int kb = ks * 32 + (lanep >> 4) * 8;
        f16x8 o;
#pragma unroll
        for (int e = 0; e < 8; ++e)
            o[e] = (f16)Wo[(size_t)(kb + e) * 128 + n];
        *reinterpret_cast<f16x8*>(&Wot[(size_t)c * 8]) = o;
    }
}

// ---- GEMM body: C[M,N] = A @ W^T (+bias); A,Wt in FRAGMENT-LINEAR --------
// MODE 1: V-proj -> Vf FRAGMENT-LINEAR (LDS bounce, window-local 16B stores)
// MODE 3: f32 partials -> out_part TILED-LINEAR (contiguous 16KB blocks)
// MODE 4: QK-proj: LDS bounce -> Qf[m][256] row-major (bx<4) or Kf fragment
//         chunks, window-local (bx>=4).
// attn fragment layouts (unchanged from R9):
//   Kf 16B unit fidx = ((h*64+jblk)*4+km)*64 + lane
//   Vf 16B unit gidx = (((h*64+jblk)*4+wd)*4+t2*2+ks)*64 + lane
template <int OUT_MODE, bool DUAL_BIAS>
static __device__ __forceinline__ void gemm_body(
    const f16* __restrict__ A, const f16* __restrict__ Wt,
    const float* __restrict__ b1, const float* __restrict__ b2,
    void* __restrict__ outp, int M, int N, int K,
    int bx, int by, int bz, int nz, void* __restrict__ outp2 = nullptr) {
    const int t = threadIdx.x;
    const int w = t >> 6, lane = t & 63, quad = lane >> 4, col = lane & 15;
    const int mb = by * 64 + (w & 1) * 32;
    const int nb = bx * 64 + (w >> 1) * 32;

    const f32x4 zero = {0.f, 0.f, 0.f, 0.f};
    f32x4 acc[2][2];
    acc[0][0] = zero; acc[0][1] = zero; acc[1][0] = zero; acc[1][1] = zero;

    const int ksteps = K >> 5;
    const int kper = ksteps / nz;
    const int ks0 = bz * kper, ks1 = ks0 + kper;
    const int rblk0 = mb >> 4, nblk0 = nb >> 4;
    for (int ks = ks0; ks < ks1; ++ks) {
        const f16x8 a0 = *reinterpret_cast<const f16x8*>(
            &A[((size_t)(rblk0 * ksteps + ks) * 64 + lane) * 8]);
        const f16x8 a1 = *reinterpret_cast<const f16x8*>(
            &A[((size_t)((rblk0 + 1) * ksteps + ks) * 64 + lane) * 8]);
        const f16x8 b0 = *reinterpret_cast<const f16x8*>(
            &Wt[((size_t)(nblk0 * ksteps + ks) * 64 + lane) * 8]);
        const f16x8 bb = *reinterpret_cast<const f16x8*>(
            &Wt[((size_t)((nblk0 + 1) * ksteps + ks) * 64 + lane) * 8]);
        acc[0][0] = __builtin_amdgcn_mfma_f32_16x16x32_f16(a0, b0, acc[0][0], 0, 0, 0);
        acc[1][0] = __builtin_amdgcn_mfma_f32_16x16x32_f16(a1, b0, acc[1][0], 0, 0, 0);
        acc[0][1] = __builtin_amdgcn_mfma_f32_16x16x32_f16(a0, bb, acc[0][1], 0, 0, 0);
        acc[1][1] = __builtin_amdgcn_mfma_f32_16x16x32_f16(a1, bb, acc[1][1], 0, 0, 0);
    }

    if constexpr (OUT_MODE == 1) {
        __shared__ f16 ct[64][68];
#pragma unroll
        for (int sub = 0; sub < 2; ++sub)
#pragma unroll
            for (int snb = 0; snb < 2; ++snb) {
                const int nl = (w >> 1) * 32 + snb * 16 + col;
                const float bv = b1[nb + snb * 16 + col];
                const int ml0 = (w & 1) * 32 + sub * 16 + quad * 4;
                uint2 u;
                u.x = pack_f16x2(acc[sub][snb][0] + bv, acc[sub][snb][1] + bv);
                u.y = pack_f16x2(acc[sub][snb][2] + bv, acc[sub][snb][3] + bv);
                *reinterpret_cast<uint2*>(&ct[nl][ml0]) = u;
            }
        __syncthreads();
        const int nl = t >> 2, qtr = t & 3;
        const int n = bx * 64 + nl;          // hd index 0..1023
        const int m0 = by * 64 + qtr * 16;   // key base
        const f16x8 v0 = *reinterpret_cast<const f16x8*>(&ct[nl][qtr * 16]);
        const f16x8 v1 = *reinterpret_cast<const f16x8*>(&ct[nl][qtr * 16 + 8]);
        const int hh = n >> 7, dd = n & 127;
        const int wdv = dd >> 5, t2v = (dd >> 4) & 1, colv = dd & 15;
        {   // v0: keys m0..m0+7
            const int m = m0;
            const int jb = m >> 6, ksv = (m >> 5) & 1, qv = (m >> 3) & 3;
            const size_t gidx = ((size_t)((((hh * 64 + jb) * 4 + wdv) * 4) + t2v * 2 + ksv)) * 64 + qv * 16 + colv;
            *reinterpret_cast<f16x8*>(&((f16*)outp)[gidx * 8]) = v0;
        }
        {   // v1: keys m0+8..m0+15
            const int m = m0 + 8;
            const int jb = m >> 6, ksv = (m >> 5) & 1, qv = (m >> 3) & 3;
            const size_t gidx = ((size_t)((((hh * 64 + jb) * 4 + wdv) * 4) + t2v * 2 + ksv)) * 64 + qv * 16 + colv;
            *reinterpret_cast<f16x8*>(&((f16*)outp)[gidx * 8]) = v1;
        }
    } else if constexpr (OUT_MODE == 4) {
        f16* Qf = (f16*)outp;
        f16* Kf = (f16*)outp2;
        __shared__ f16 ct[64][72];   // [m_local][n_local]
#pragma unroll
        for (int sub = 0; sub < 2; ++sub)
#pragma unroll
            for (int snb = 0; snb < 2; ++snb) {
                const int n = nb + snb * 16 + col;
                const float bv = (DUAL_BIAS && n >= 256) ? b2[n - 256] : b1[n];
                const int nl = (w >> 1) * 32 + snb * 16 + col;
                const int ml0 = (w & 1) * 32 + sub * 16 + quad * 4;
#pragma unroll
                for (int reg = 0; reg < 4; ++reg)
                    ct[ml0 + reg][nl] = (f16)(acc[sub][snb][reg] + bv);
            }
        __syncthreads();
        if (bx < 4) {
            // pure Q region: row-major Qf[m][256], coalesced f16x8 runs
#pragma unroll
            for (int p = 0; p < 2; ++p) {
                const int C = p * 256 + t;           // 512 f16x8 chunks
                const int r = C >> 3, c8 = (C & 7) * 8;
                const f16x8 v = *reinterpret_cast<const f16x8*>(&ct[r][c8]);
                *reinterpret_cast<f16x8*>(
                    &Qf[(size_t)(by * 64 + r) * 256 + bx * 64 + c8]) = v;
            }
        } else {
            // K region: fragment 16B chunks, window-local stores
#pragma unroll
            for (int p = 0; p < 2; ++p) {
                const int C = p * 256 + t;
                const int r = C >> 3, c8 = (C & 7) * 8;   // key_local, d64
                const int key = by * 64 + r;
                const int hh = (bx - 4) * 2 + (c8 >> 5);
                const int dd = c8 & 31;
                const f16x8 v = *reinterpret_cast<const f16x8*>(&ct[r][c8]);
                const int lane_k = (dd >> 3) * 16 + ((key >> 2) & 15);
                const size_t fidx =
                    ((size_t)(hh * 64 + (key >> 6)) * 4 + (key & 3)) * 64 + lane_k;
                *reinterpret_cast<f16x8*>(&Kf[fidx * 8]) = v;
            }
        }
    } else {
        // MODE 3: tiled-linear out_part
        __shared__ float cs[64][65];
#pragma unroll
        for (int sub = 0; sub < 2; ++sub)
#pragma unroll
            for (int snb = 0; snb < 2; ++snb) {
                const int nl = (w >> 1) * 32 + snb * 16 + col;
                const int ml0 = (w & 1) * 32 + sub * 16 + quad * 4;
#pragma unroll
                for (int reg = 0; reg < 4; ++reg)
                    cs[ml0 + reg][nl] = acc[sub][snb][reg];
            }
        __syncthreads();
        float* tb = (float*)outp + (size_t)(bz * 128 + by * 2 + bx) * 4096;
#pragma unroll
        for (int p = 0; p < 4; ++p) {
            const int F = p * 256 + t;            // 1024 float4 chunks
            const int r = F >> 4, c4 = (F & 15) * 4;
            float4 v;
            v.x = cs[r][c4]; v.y = cs[r][c4 + 1];
            v.z = cs[r][c4 + 2]; v.w = cs[r][c4 + 3];
            *reinterpret_cast<float4*>(&tb[(size_t)F * 4]) = v;
        }
    }
}

// ---- fused QK + V projections (one launch, 24x64 grid) -------------------
__global__ __launch_bounds__(256) void proj_kernel(
    const f16* __restrict__ xf, const f16* __restrict__ Wqkt,
    const f16* __restrict__ Wvt,
    const float* __restrict__ bq, const float* __restrict__ bk,
    const float* __restrict__ bv,
    f16* __restrict__ Qf, f16* __restrict__ Kf, f16* __restrict__ Vf) {
    if (blockIdx.x < 8)
        gemm_body<4, true>(xf, Wqkt, bq, bk, Qf, N_NODES, 512, D_MODEL,
                           blockIdx.x, blockIdx.y, 0, 1, Kf);
    else
        gemm_body<1, false>(xf, Wvt, bv, bv, Vf, N_NODES, VH, D_MODEL,
                            blockIdx.x - 8, blockIdx.y, 0, 1);
}

// ---- out-projection with k-split (tiled-linear partials) -----------------
__global__ __launch_bounds__(256) void outproj_kernel(
    const f16* __restrict__ Rf, const f16* __restrict__ Wot,
    float* __restrict__ outp) {
    gemm_body<3, false>(Rf, Wot, nullptr, nullptr, outp, N_NODES, D_MODEL, VH,
                        blockIdx.x, blockIdx.y, blockIdx.z, gridDim.z);
}

// ---- MFMA flash attention: R12 structure + VALU-diet epilogue ------------
// HISTORY: R1 252us spill / R2,R3 WRONG @(256,2) / R5 172.8us / R6 573MB
// spill / R7 NaN (pipeline edits fragile -> sync structure FROZEN) / R8
// traffic theory refuted / R9 frag-linear K,V loads: 105.5us / R10 dead-
// branch perturbation (rule #19) / R11 templated epilogue / R12 store fixes
// null -> non-attn residual is fixed harness overhead; attn VALU-limited
// (VALUBusy 53%). R13/R14: epilogue VALU diet (sync/loads byte-identical):
//   (a) nibble mask extract: one u64 shift per reg, per-score test is
//       and-const+cmp+cndmask (was per-score 64-bit variable shift chain)
//   (b) ps pack via v_cvt_pkrtz_f16_f32 (1 instr per pair, was ~3)
//   (c) bias pre-folded (bias*L2E + C8) at LOADB time, off the critical path
#define FENCED_BARRIER() do { \
    asm volatile("s_waitcnt lgkmcnt(0)\n\ts_barrier" ::: "memory"); \
    __builtin_amdgcn_sched_barrier(0); \
} while (0)

#define LOADK(KB, J) do { _Pragma("unroll") \
    for (int km = 0; km < 4; ++km) \
        KB[km] = *reinterpret_cast<const f16x8*>( \
            &Kf[((size_t)((h * 64 + ((J) >> 6)) * 4 + km) * 64 + lane) * 8]); } while (0)

#define LOADV(VB, J) do { _Pragma("unroll") \
    for (int t2 = 0; t2 < 2; ++t2) { _Pragma("unroll") \
        for (int ks = 0; ks < 2; ++ks) \
            VB[t2][ks] = *reinterpret_cast<const f16x8*>( \
                &Vf[((size_t)(((h * 64 + ((J) >> 6)) * 4 + w) * 4 + t2 * 2 + ks) * 64 + lane) * 8]); } } while (0)

#define LOADM(J) do { _Pragma("unroll") \
    for (int reg = 0; reg < 4; ++reg) \
        mr[reg] = mbits[(size_t)(q0 + 16 * w + quad * 4 + reg) * 64 + ((J) >> 6)]; } while (0)

#define LOADB(J) do { _Pragma("unroll") \
    for (int reg = 0; reg < 4; ++reg) { \
        const float4 b4 = *reinterpret_cast<const float4*>( \
            &bias[(size_t)(q0 + 16 * w + quad * 4 + reg) * N_NODES + (J) + 4 * col]); \
        bfr[reg][0] = __builtin_fmaf(b4.x, L2E, C8); \
        bfr[reg][1] = __builtin_fmaf(b4.y, L2E, C8); \
        bfr[reg][2] = __builtin_fmaf(b4.z, L2E, C8); \
        bfr[reg][3] = __builtin_fmaf(b4.w, L2E, C8); } } while (0)

#define TILE(KB, PSEL, PJ, POK, VJ, MJ, MOK) do { \
    f32x4 S[4]; \
    _Pragma("unroll") \
    for (int km = 0; km < 4; ++km) \
        S[km] = __builtin_amdgcn_mfma_f32_16x16x32_f16(qa, KB[km], zero, 0, 0, 0); \
    if (POK) LOADK(KB, PJ); \
    LOADV(vbT, VJ); \
    _Pragma("unroll") \
    for (int reg = 0; reg < 4; ++reg) { \
        const unsigned int nib = ((unsigned int)(mr[reg] >> (4 * col))) & 0xFu; \
        float pk[4]; \
        _Pragma("unroll") \
        for (int km = 0; km < 4; ++km) { \
            const float base = (h == 0) ? bfr[reg][km] : C8; \
            const float tt = __builtin_fmaf(S[km][reg], SCL, base); \
            pk[km] = (nib & (1u << km)) ? 0.f : __builtin_amdgcn_exp2f(tt); \
        } \
        uint2 u; \
        u.x = pkrtz(pk[0], pk[1]); \
        u.y = pkrtz(pk[2], pk[3]); \
        *reinterpret_cast<uint2*>(&ps[PSEL][16 * w + quad * 4 + reg][4 * col]) = u; \
    } \
    if (MOK) { LOADM(MJ); if (h == 0) LOADB(MJ); } \
    FENCED_BARRIER(); \
    __builtin_amdgcn_s_setprio(1); \
    _Pragma("unroll") \
    for (int ks = 0; ks < 2; ++ks) { _Pragma("unroll") \
        for (int qs = 0; qs < 4; ++qs) { \
            const f16x8 pa = *reinterpret_cast<const f16x8*>( \
                &ps[PSEL][16 * qs + col][ks * 32 + quad * 8]); \
            if (qs == w) \
                Lacc = __builtin_amdgcn_mfma_f32_16x16x32_f16(pa, onesv, Lacc, 0, 0, 0); \
            O[qs][0] = __builtin_amdgcn_mfma_f32_16x16x32_f16(pa, vbT[0][ks], O[qs][0], 0, 0, 0); \
            O[qs][1] = __builtin_amdgcn_mfma_f32_16x16x32_f16(pa, vbT[1][ks], O[qs][1], 0, 0, 0); \
        } } \
    __builtin_amdgcn_s_setprio(0); \
} while (0)

template <bool SPLIT>
__global__ __launch_bounds__(256, 3) void attn_kernel(
    const f16* __restrict__ Qf, const f16* __restrict__ Kf,
    const f16* __restrict__ Vf,
    const u64* __restrict__ mbits, const float* __restrict__ bias,
    f16* __restrict__ R, f16* __restrict__ part, float* __restrict__ lsum) {
    const int h  = blockIdx.y;
    const int q0 = blockIdx.x * 64;
    const int t  = threadIdx.x;
    const int w = t >> 6, lane = t & 63, quad = lane >> 4, col = lane & 15;

    __shared__ f16 ps[2][64][72];   // double-buffered P tile
    __shared__ float ls[64];        // row sums for final normalization

    const f16x8 qa = *reinterpret_cast<const f16x8*>(
        &Qf[(size_t)(q0 + 16 * w + col) * 256 + h * 32 + quad * 8]);

    const f32x4 zero = {0.f, 0.f, 0.f, 0.f};
    f32x4 O[4][2];               // [qs][t2]: q 16qs+quad*4+reg, d 32w+16t2+col
#pragma unroll
    for (int qs = 0; qs < 4; ++qs) { O[qs][0] = zero; O[qs][1] = zero; }
    f32x4 Lacc = zero;
    const f16 one1 = (f16)1.f;
    const f16x8 onesv = {one1, one1, one1, one1, one1, one1, one1, one1};

    const float L2E = 1.4426950408889634f;
    const float SCL = 0.17677669529663687f * 1.4426950408889634f;  // scale*log2e
    const float C8  = -8.f * 1.4426950408889634f;                  // -MFIX*log2e
    const int jspan = N_NODES / gridDim.z;
    const int jbegin = blockIdx.z * jspan, jend = jbegin + jspan;

    f16x8 kbA[4], kbB[4];
    f16x8 vbT[2][2];
    u64   mr[4];
    float bfr[4][4];

    // prologue: two tiles of K, one tile of mask/bias (V loads in-tile)
    LOADK(kbA, jbegin);
    LOADK(kbB, jbegin + 64);
    LOADM(jbegin);
    if (h == 0) LOADB(jbegin);

    for (int j0 = jbegin; j0 < jend; j0 += 128) {
        TILE(kbA, 0, j0 + 128, j0 + 128 < jend, j0,      j0 + 64,  true);
        TILE(kbB, 1, j0 + 192, j0 + 192 < jend, j0 + 64, j0 + 128, j0 + 128 < jend);
    }

    // --- exchange row sums, normalize, store ---
    if (col == 0) {
#pragma unroll
        for (int reg = 0; reg < 4; ++reg)
            ls[16 * w + quad * 4 + reg] = Lacc[reg];
    }
    __syncthreads();

    if constexpr (SPLIT) {
        const size_t seg = (size_t)(blockIdx.z * NHEAD + h) * N_NODES;
#pragma unroll
        for (int qs = 0; qs < 4; ++qs)
#pragma unroll
            for (int reg = 0; reg < 4; ++reg) {
                const float inv = 1.f / ls[16 * qs + quad * 4 + reg];
                const int q = q0 + 16 * qs + quad * 4 + reg;
#pragma unroll
                for (int t2 = 0; t2 < 2; ++t2)
                    part[(seg + q) * 128 + 32 * w + 16 * t2 + col] =
                        (f16)(O[qs][t2][reg] * inv);
            }
        if (col == 0) {
#pragma unroll
            for (int reg = 0; reg < 4; ++reg)
                lsum[seg + q0 + 16 * w + quad * 4 + reg] = Lacc[reg];
        }
    } else {
        // direct fragment-linear Rf store (tiny-ws fallback only)
#pragma unroll
        for (int qs = 0; qs < 4; ++qs)
#pragma unroll
            for (int reg = 0; reg < 4; ++reg) {
                const float inv = 1.f / ls[16 * qs + quad * 4 + reg];
                const int q = q0 + 16 * qs + quad * 4 + reg;
#pragma unroll
                for (int t2 = 0; t2 < 2; ++t2) {
                    const int hd = h * 128 + 32 * w + 16 * t2 + col;
                    const size_t c = ((size_t)(q >> 4) * 32 + (hd >> 5)) * 64 +
                                     ((hd >> 3) & 3) * 16 + (q & 15);
                    R[c * 8 + (hd & 7)] = (f16)(O[qs][t2][reg] * inv);
                }
            }
    }
}

// ---- merge split partials: R = sum_z l_z*Obar_z / sum_z l_z --------------
// vectorized f16x8; writes Rf FRAGMENT-LINEAR for outproj's A-fragment loads
__global__ __launch_bounds__(256) void merge_kernel(
    const f16* __restrict__ part, const float* __restrict__ lsum,
    f16* __restrict__ R, int split) {
    const int tid = blockIdx.x * 256 + threadIdx.x;   // 8*4096*16
    const int d8 = tid & 15, q = (tid >> 4) & 4095, h = tid >> 16;
    float acc[8];
#pragma unroll
    for (int i = 0; i < 8; ++i) acc[i] = 0.f;
    float den = 0.f;
    for (int z = 0; z < split; ++z) {
        const size_t seg = (size_t)(z * NHEAD + h) * N_NODES + q;
        const float l = lsum[seg];
        const f16x8 v = *reinterpret_cast<const f16x8*>(&part[seg * 128 + 8 * d8]);
#pragma unroll
        for (int i = 0; i < 8; ++i) acc[i] += l * (float)v[i];
        den += l;
    }
    const float inv = 1.f / den;
    f16x8 o;
#pragma unroll
    for (int i = 0; i < 8; ++i) o[i] = (f16)(acc[i] * inv);
    // hd0 = h*128 + 8*d8 -> chunk c = (rblk*32 + ks)*64 + quad'*16 + col'
    const size_t c = ((size_t)(q >> 4) * 32 + h * 4 + (d8 >> 2)) * 64 +
                     (d8 & 3) * 16 + (q & 15);
    *reinterpret_cast<f16x8*>(&R[c * 8]) = o;
}

// ---- reduce out-proj tiled partials + bias (float4, coalesced) -----------
__global__ __launch_bounds__(256) void reduce_out_kernel(
    const float* __restrict__ part, const float* __restrict__ bo,
    float* __restrict__ out) {
    const int i = (blockIdx.x * 256 + threadIdx.x) * 4;   // 4096*128 floats
    const int q = i >> 7, n = i & 127;
    const size_t telem = (size_t)(q & 63) * 64 + (n & 63);
    float4 s = *reinterpret_cast<const float4*>(&bo[n]);
#pragma unroll
    for (int z = 0; z < 4; ++z) {
        const float* tb = part +
            (size_t)(z * 128 + (q >> 6) * 2 + (n >> 6)) * 4096;
        const float4 p = *reinterpret_cast<const float4*>(&tb[telem]);
        s.x += p.x; s.y += p.y; s.z += p.z; s.w += p.w;
    }
    *reinterpret_cast<float4*>(&out[i]) = s;
}

extern "C" void kernel_launch(void* const* d_in, const int* in_sizes, int n_in,
                              void* d_out, int out_size, void* d_ws, size_t ws_size,
                              hipStream_t stream) {
    const float* x  = (const float*)d_in[0];
    const int*   mk = (const int*)d_in[1];
    const float* eb = (const float*)d_in[2];
    const float* Wq = (const float*)d_in[3];
    const float* bq = (const float*)d_in[4];
    const float* Wk = (const float*)d_in[5];
    const float* bk = (const float*)d_in[6];
    const float* Wv = (const float*)d_in[7];
    const float* bv = (const float*)d_in[8];
    const float* Wo = (const float*)d_in[9];
    const float* bo = (const float*)d_in[10];
    float* out = (float*)d_out;

    char* ws = (char*)d_ws;
    u64* mbits = (u64*)(ws);                                    // 2 MB
    f16* xf16 = (f16*)(ws + 2097152);                           // 1 MB frag
    f16* Wqkt = (f16*)(ws + 3145728);                           // 128 KB frag
    f16* Wvt  = (f16*)(ws + 3276800);                           // 256 KB frag
    f16* Wot  = (f16*)(ws + 3538944);                           // 256 KB frag
    f16* Qf   = (f16*)(ws + 3801088);                           // 2 MB (node x 256)
    f16* Kf   = (f16*)(ws + 5898240);                           // 2 MB fragment-linear
    f16* Vf   = (f16*)(ws + 7995392);                           // 8 MB fragment-linear
    f16* Rf   = (f16*)(ws + 16384000);                          // 8 MB frag -> 24772608
    float* out_part = (float*)(ws + 24772608);                  // 8 MB tiled -> 33161216
    float* lsum = (float*)(ws + 33161216);                      // 512 KB -> 33685504
    f16* part = (f16*)(ws + 33685504);                          // split*8MB -> 67239936

    // config from ws_size only (constant across calls -> graph-safe)
    int split = 1;
    if (ws_size >= 67239936ull) split = 4;
    else if (ws_size >= 50462720ull) split = 2;
    // part path needs part segment (split*8MB after 33685504) + lsum
    const bool use_part = ws_size >= 33685504ull + (size_t)split * 8388608ull;
    const bool ksplit_out = ws_size >= 33161216ull;

    prep_kernel<<<1440, 256, 0, stream>>>(mk, mbits, x, xf16, Wq, Wk, Wqkt, Wv, Wvt, Wo, Wot);

    proj_kernel<<<dim3(24, 64), 256, 0, stream>>>(xf16, Wqkt, Wvt, bq, bk, bv, Qf, Kf, Vf);

    if (use_part) {
        attn_kernel<true><<<dim3(64, 8, split), 256, 0, stream>>>(
            Qf, Kf, Vf, mbits, eb, Rf, part, lsum);
        merge_kernel<<<2048, 256, 0, stream>>>(part, lsum, Rf, split);
    } else {
        attn_kernel<false><<<dim3(64, 8, 1), 256, 0, stream>>>(
            Qf, Kf, Vf, mbits, eb, Rf, part, lsum);
    }

    if (ksplit_out) {
        outproj_kernel<<<dim3(2, 64, 4), 256, 0, stream>>>(Rf, Wot, out_part);
        reduce_out_kernel<<<512, 256, 0, stream>>>(out_part, bo, out);
    } else {
        // fallback: single-pass out-projection (never taken at bench ws)
        outproj_kernel<<<dim3(2, 64, 1), 256, 0, stream>>>(Rf, Wot, out_part);
        reduce_out_kernel<<<512, 256, 0, stream>>>(out_part, bo, out);
    }
}